// Round 1
// baseline (7714.803 us; speedup 1.0000x reference)
//
#include <hip/hip_runtime.h>
#include <math.h>

#define B_   512
#define T_   800
#define FIN  3
#define NF   128
#define KW   15
#define HID  150
#define LOUT 393
#define G4   600
#define NPAD 640
#define EPS  1e-5f

__device__ __forceinline__ float hsig(float x){ return fminf(fmaxf(0.2f*x+0.5f,0.f),1.f); }

// ---------------- conv + relu + maxpool2 -> y[b][l][c] ----------------
__global__ __launch_bounds__(512) void k_conv(const float* __restrict__ x,
        const float* __restrict__ cw, const float* __restrict__ cb,
        float* __restrict__ y){
  __shared__ float wl[NF*FIN*KW];     // 5760
  __shared__ float xl[FIN][24];
  int tid = threadIdx.x;
  int b = blockIdx.y;
  int l0 = blockIdx.x*4;
  for (int i=tid;i<NF*FIN*KW;i+=512) wl[i]=cw[i];
  if (tid < FIN*22){ int f=tid/22, j=tid%22; int p = 2*l0+j;
     xl[f][j] = (p<T_)? x[(size_t)b*(FIN*T_) + (size_t)f*T_ + p] : 0.f; }
  __syncthreads();
  int c = tid & 127, li = tid >> 7;
  int l = l0 + li;
  if (l >= LOUT) return;
  float wr[FIN*KW];
  #pragma unroll
  for (int i=0;i<FIN*KW;i++) wr[i]=wl[c*FIN*KW+i];
  float xv[FIN][16];
  #pragma unroll
  for (int f=0;f<FIN;f++){
    #pragma unroll
    for (int j=0;j<16;j++) xv[f][j]=xl[f][2*li+j];
  }
  float a0=0.f,a1=0.f;
  #pragma unroll
  for (int f=0;f<FIN;f++){
    #pragma unroll
    for (int k=0;k<KW;k++){ float w=wr[f*KW+k]; a0 += w*xv[f][k]; a1 += w*xv[f][k+1]; }
  }
  float v = fmaxf(fmaxf(a0,a1)+cb[c], 0.f);
  y[((size_t)b*LOUT + l)*NF + c] = v;
}

// ---------------- per-channel stats over (b,l) ----------------
__global__ void k_stats1(const float* __restrict__ y, float* __restrict__ st){
  int tid = threadIdx.x;  // 256
  int c = tid & 127;
  size_t N = (size_t)B_*LOUT*NF;
  float s=0.f,q=0.f;
  for (size_t i = (size_t)blockIdx.x*256 + tid; i < N; i += (size_t)256*256){
    float v = y[i]; s += v; q += v*v;
  }
  __shared__ float ls[512];
  ls[tid]=s; ls[256+tid]=q; __syncthreads();
  if (tid<128){
    atomicAdd(&st[c],     ls[tid]+ls[tid+128]);
    atomicAdd(&st[128+c], ls[256+tid]+ls[256+tid+128]);
  }
}

// -------- fold AdaBN1 into projection weights: wT[f][n], bias_eff[n] --------
__global__ void k_prep(const float* __restrict__ st,
    const float* __restrict__ g1, const float* __restrict__ b1v,
    const float* __restrict__ wf, const float* __restrict__ wb,
    const float* __restrict__ bif, const float* __restrict__ bhf,
    const float* __restrict__ bib, const float* __restrict__ bhb,
    float* __restrict__ wTf, float* __restrict__ wTb,
    float* __restrict__ bef, float* __restrict__ beb){
  int id = blockIdx.x*256 + threadIdx.x;
  if (id >= 2*NPAD) return;
  int dir = id/NPAD, g = id%NPAD;
  float* wT = dir? wTb : wTf;
  float* be = dir? beb : bef;
  if (g >= G4){ for (int f=0;f<NF;f++) wT[(size_t)f*NPAD+g]=0.f; be[g]=0.f; return; }
  const float* wih = dir? wb : wf;
  float bias = dir? (bib[g]+bhb[g]) : (bif[g]+bhf[g]);
  const float Ninv = 1.f/((float)B_*(float)LOUT);
  for (int f=0;f<NF;f++){
    float m = st[f]*Ninv;
    float var = st[NF+f]*Ninv - m*m;
    float a = g1[f]*rsqrtf(var+EPS);
    float d = b1v[f] - m*a;
    float w = wih[g*NF+f];
    wT[(size_t)f*NPAD+g] = a*w;
    bias += d*w;
  }
  be[g] = bias;
}

// ---------------- projection GEMM: pre[trel*512+b][n] = y[b][t].wT + be ----------------
__global__ __launch_bounds__(256) void k_proj(const float* __restrict__ y,
    const float* __restrict__ wT, const float* __restrict__ be,
    float* __restrict__ pre, int t0, int tsgn, int tc){
  __shared__ float As[NF][68];
  __shared__ float Bs[NF][68];
  int tid = threadIdx.x;
  int m0 = blockIdx.x*64, n0 = blockIdx.y*64;
  int trel = m0 >> 9, bb = m0 & 511;
  int t = t0 + tsgn*trel;
  {
    int r = tid>>5, cg = tid&31;
    #pragma unroll
    for (int i=0;i<8;i++){
      int rr = r + i*8;
      const float* src = y + ((size_t)(bb+rr)*LOUT + t)*NF + cg*4;
      float4 v = *(const float4*)src;
      As[cg*4+0][rr]=v.x; As[cg*4+1][rr]=v.y; As[cg*4+2][rr]=v.z; As[cg*4+3][rr]=v.w;
    }
    int k0 = tid>>4, n4 = tid&15;
    #pragma unroll
    for (int i=0;i<8;i++){
      int k = k0 + i*16;
      *(float4*)&Bs[k][n4*4] = *(const float4*)&wT[(size_t)k*NPAD + n0 + n4*4];
    }
  }
  __syncthreads();
  int rm = (tid&15)*4, cn = (tid>>4)*4;
  float acc[4][4]={};
  #pragma unroll 8
  for (int k=0;k<NF;k++){
    float4 av = *(const float4*)&As[k][rm];
    float4 bv = *(const float4*)&Bs[k][cn];
    float a4[4]={av.x,av.y,av.z,av.w};
    float b4[4]={bv.x,bv.y,bv.z,bv.w};
    #pragma unroll
    for (int i=0;i<4;i++){
      #pragma unroll
      for (int j=0;j<4;j++) acc[i][j] += a4[i]*b4[j];
    }
  }
  float4 bias = *(const float4*)&be[n0+cn];
  float bi[4]={bias.x,bias.y,bias.z,bias.w};
  #pragma unroll
  for (int i=0;i<4;i++){
    int m = m0 + rm + i;
    float4 o; o.x=acc[i][0]+bi[0]; o.y=acc[i][1]+bi[1]; o.z=acc[i][2]+bi[2]; o.w=acc[i][3]+bi[3];
    *(float4*)&pre[(size_t)m*NPAD + n0 + cn] = o;
  }
}

// ---------------- recurrence: register-resident w_hh, fused time-max ----------------
__global__ __launch_bounds__(512) void k_rec(const float* __restrict__ whf,
    const float* __restrict__ whb,
    const float* __restrict__ pref, const float* __restrict__ preb,
    float* __restrict__ hst, float* __restrict__ cst, float* __restrict__ mst,
    float* __restrict__ pooled, int tc, int first, int last){
  int dir = blockIdx.x >> 7;
  int b0 = (blockIdx.x & 127)*4;
  const float* wh  = dir? whb : whf;
  const float* pre = dir? preb : pref;
  int tid = threadIdx.x;
  int lane = tid & 63, wv = tid >> 6;
  int gl = lane & 15, kl = lane >> 4;
  int gbase = wv*75 + gl*5;
  int kq = kl*10;

  __shared__ float hls[4][160];
  __shared__ float smem[22528];
  float (*dls)[608]    = (float(*)[608])smem;                 // 4*608
  float (*pls)[4][608] = (float(*)[4][608])(smem + 4*608);    // 2*4*608

  // weights -> registers via coalesced LDS staging
  float w[5][40];
  #pragma unroll
  for (int i=0;i<5;i++){
    #pragma unroll
    for (int j=0;j<40;j++) w[i][j]=0.f;
  }
  for (int s=0;s<4;s++){
    const float* src = wh + (size_t)s*150*HID;
    for (int i=tid;i<150*HID;i+=512) smem[i]=src[i];
    __syncthreads();
    if (gl<15 && gbase >= s*150 && gbase < s*150+150){
      int go = gbase - s*150;
      #pragma unroll
      for (int i=0;i<5;i++){
        #pragma unroll
        for (int j=0;j<40;j++){
          int k = kl*40+j;
          if (k < HID) w[i][j] = smem[(go+i)*HID + k];
        }
      }
    }
    __syncthreads();
  }

  int u1 = tid % 150, b1 = tid / 150;
  int u2 = (tid+512) % 150, b2 = (tid+512) / 150;
  bool has2 = tid < 88;
  float cr0, cr1=0.f, mr0, mr1=-1e30f;
  if (first){
    cr0=0.f; mr0=-1e30f;
    for (int i=tid;i<4*160;i+=512) (&hls[0][0])[i]=0.f;
  } else {
    cr0 = cst[((size_t)dir*B_ + b0+b1)*HID + u1];
    mr0 = mst[((size_t)dir*B_ + b0+b1)*HID + u1];
    if (has2){
      cr1 = cst[((size_t)dir*B_ + b0+b2)*HID + u2];
      mr1 = mst[((size_t)dir*B_ + b0+b2)*HID + u2];
    }
    for (int i=tid;i<4*160;i+=512){ int bq=i/160, uu=i%160;
      (&hls[0][0])[i] = (uu<HID)? hst[((size_t)dir*B_ + b0+bq)*HID+uu] : 0.f; }
  }
  // preload pre[0]
  #pragma unroll
  for (int bq=0;bq<4;bq++) pls[0][bq][tid] = pre[((size_t)(b0+bq))*NPAD + tid];
  if (has2){
    #pragma unroll
    for (int bq=0;bq<4;bq++) pls[0][bq][512+tid] = pre[((size_t)(b0+bq))*NPAD + 512+tid];
  }
  __syncthreads();

  int cur=0;
  for (int t=0;t<tc;t++){
    const float4* h40 = (const float4*)&hls[0][0];
    const float4* h41 = (const float4*)&hls[1][0];
    const float4* h42 = (const float4*)&hls[2][0];
    const float4* h43 = (const float4*)&hls[3][0];
    // half 0: batches 0,1
    {
      float acc[5][2];
      #pragma unroll
      for (int i=0;i<5;i++){acc[i][0]=0.f;acc[i][1]=0.f;}
      #pragma unroll
      for (int q=0;q<10;q++){
        float4 ha = h40[kq+q], hb = h41[kq+q];
        #pragma unroll
        for (int i=0;i<5;i++){
          acc[i][0] += w[i][4*q]*ha.x + w[i][4*q+1]*ha.y + w[i][4*q+2]*ha.z + w[i][4*q+3]*ha.w;
          acc[i][1] += w[i][4*q]*hb.x + w[i][4*q+1]*hb.y + w[i][4*q+2]*hb.z + w[i][4*q+3]*hb.w;
        }
      }
      #pragma unroll
      for (int i=0;i<5;i++){
        acc[i][0] += __shfl_xor(acc[i][0],16); acc[i][0] += __shfl_xor(acc[i][0],32);
        acc[i][1] += __shfl_xor(acc[i][1],16); acc[i][1] += __shfl_xor(acc[i][1],32);
      }
      if (kl==0 && gl<15){
        #pragma unroll
        for (int i=0;i<5;i++){ dls[0][gbase+i]=acc[i][0]; dls[1][gbase+i]=acc[i][1]; }
      }
    }
    // half 1: batches 2,3
    {
      float acc[5][2];
      #pragma unroll
      for (int i=0;i<5;i++){acc[i][0]=0.f;acc[i][1]=0.f;}
      #pragma unroll
      for (int q=0;q<10;q++){
        float4 ha = h42[kq+q], hb = h43[kq+q];
        #pragma unroll
        for (int i=0;i<5;i++){
          acc[i][0] += w[i][4*q]*ha.x + w[i][4*q+1]*ha.y + w[i][4*q+2]*ha.z + w[i][4*q+3]*ha.w;
          acc[i][1] += w[i][4*q]*hb.x + w[i][4*q+1]*hb.y + w[i][4*q+2]*hb.z + w[i][4*q+3]*hb.w;
        }
      }
      #pragma unroll
      for (int i=0;i<5;i++){
        acc[i][0] += __shfl_xor(acc[i][0],16); acc[i][0] += __shfl_xor(acc[i][0],32);
        acc[i][1] += __shfl_xor(acc[i][1],16); acc[i][1] += __shfl_xor(acc[i][1],32);
      }
      if (kl==0 && gl<15){
        #pragma unroll
        for (int i=0;i<5;i++){ dls[2][gbase+i]=acc[i][0]; dls[3][gbase+i]=acc[i][1]; }
      }
    }
    // prefetch next pre
    float pn[4]={0,0,0,0}, pn2[4]={0,0,0,0};
    bool ld = (t+1 < tc);
    if (ld){
      #pragma unroll
      for (int bq=0;bq<4;bq++) pn[bq] = pre[((size_t)(t+1)*B_ + b0+bq)*NPAD + tid];
      if (has2){
        #pragma unroll
        for (int bq=0;bq<4;bq++) pn2[bq] = pre[((size_t)(t+1)*B_ + b0+bq)*NPAD + 512+tid];
      }
    }
    __syncthreads();
    // phase B: gates, cell update, running max
    {
      float ig = hsig (dls[b1][u1]      + pls[cur][b1][u1]);
      float fg = hsig (dls[b1][150+u1]  + pls[cur][b1][150+u1]);
      float gg = tanhf(dls[b1][300+u1]  + pls[cur][b1][300+u1]);
      float og = hsig (dls[b1][450+u1]  + pls[cur][b1][450+u1]);
      cr0 = fg*cr0 + ig*gg;
      float hv = og*tanhf(cr0);
      mr0 = fmaxf(mr0,hv);
      hls[b1][u1] = hv;
      if (has2){
        float ig2 = hsig (dls[b2][u2]      + pls[cur][b2][u2]);
        float fg2 = hsig (dls[b2][150+u2]  + pls[cur][b2][150+u2]);
        float gg2 = tanhf(dls[b2][300+u2]  + pls[cur][b2][300+u2]);
        float og2 = hsig (dls[b2][450+u2]  + pls[cur][b2][450+u2]);
        cr1 = fg2*cr1 + ig2*gg2;
        float hv2 = og2*tanhf(cr1);
        mr1 = fmaxf(mr1,hv2);
        hls[b2][u2] = hv2;
      }
    }
    if (ld){
      int nx = cur^1;
      #pragma unroll
      for (int bq=0;bq<4;bq++) pls[nx][bq][tid]=pn[bq];
      if (has2){
        #pragma unroll
        for (int bq=0;bq<4;bq++) pls[nx][bq][512+tid]=pn2[bq];
      }
    }
    __syncthreads();
    cur ^= 1;
  }
  hst[((size_t)dir*B_ + b0+b1)*HID+u1] = hls[b1][u1];
  cst[((size_t)dir*B_ + b0+b1)*HID+u1] = cr0;
  mst[((size_t)dir*B_ + b0+b1)*HID+u1] = mr0;
  if (has2){
    hst[((size_t)dir*B_ + b0+b2)*HID+u2] = hls[b2][u2];
    cst[((size_t)dir*B_ + b0+b2)*HID+u2] = cr1;
    mst[((size_t)dir*B_ + b0+b2)*HID+u2] = mr1;
  }
  if (last){
    pooled[(size_t)(b0+b1)*300 + dir*HID + u1] = mr0;
    if (has2) pooled[(size_t)(b0+b2)*300 + dir*HID + u2] = mr1;
  }
}

// ---------------- tail: AdaBN2 stats ----------------
__global__ void k_stats2(const float* __restrict__ pooled,
    const float* __restrict__ g2, const float* __restrict__ b2,
    float* __restrict__ a2, float* __restrict__ d2){
  int f = threadIdx.x;
  if (f >= 300) return;
  float s=0.f,q=0.f;
  for (int b=0;b<B_;b++){ float v = pooled[(size_t)b*300+f]; s+=v; q+=v*v; }
  float m = s*(1.f/B_), var = q*(1.f/B_) - m*m;
  float a = g2[f]*rsqrtf(var+EPS);
  a2[f]=a; d2[f]=b2[f]-m*a;
}

// ---------------- fc1 (+folded AdaBN2) + relu ----------------
__global__ void k_fc1(const float* __restrict__ pooled,
    const float* __restrict__ a2, const float* __restrict__ d2,
    const float* __restrict__ w1, const float* __restrict__ fb1,
    float* __restrict__ z1){
  int o = blockIdx.x*256 + threadIdx.x;
  if (o >= B_*50) return;
  int b = o/50, j = o%50;
  float acc = fb1[j];
  for (int f=0;f<300;f++)
    acc += (a2[f]*pooled[(size_t)b*300+f] + d2[f]) * w1[j*300+f];
  z1[o] = fmaxf(acc,0.f);
}

// ---------------- AdaBN3 stats ----------------
__global__ void k_stats3(const float* __restrict__ z1,
    const float* __restrict__ g3, const float* __restrict__ b3,
    float* __restrict__ a3, float* __restrict__ d3){
  int f = threadIdx.x;
  if (f >= 50) return;
  float s=0.f,q=0.f;
  for (int b=0;b<B_;b++){ float v = z1[(size_t)b*50+f]; s+=v; q+=v*v; }
  float m = s*(1.f/B_), var = q*(1.f/B_) - m*m;
  float a = g3[f]*rsqrtf(var+EPS);
  a3[f]=a; d3[f]=b3[f]-m*a;
}

// ---------------- fc2 (+folded AdaBN3) + softmax ----------------
__global__ void k_fc2(const float* __restrict__ z1,
    const float* __restrict__ a3, const float* __restrict__ d3,
    const float* __restrict__ w2, const float* __restrict__ fb2,
    float* __restrict__ out){
  int b = blockIdx.x;
  int t = threadIdx.x;
  __shared__ float zl[50];
  __shared__ float lg[10];
  if (t<50) zl[t] = a3[t]*z1[(size_t)b*50+t] + d3[t];
  __syncthreads();
  if (t<10){
    float acc = fb2[t];
    for (int j=0;j<50;j++) acc += zl[j]*w2[t*50+j];
    lg[t]=acc;
  }
  __syncthreads();
  if (t<10){
    float m = lg[0];
    #pragma unroll
    for (int i=1;i<10;i++) m = fmaxf(m,lg[i]);
    float s = 0.f;
    #pragma unroll
    for (int i=0;i<10;i++) s += expf(lg[i]-m);
    out[(size_t)b*10+t] = expf(lg[t]-m)/s;
  }
}

extern "C" void kernel_launch(void* const* d_in, const int* in_sizes, int n_in,
                              void* d_out, int out_size, void* d_ws, size_t ws_size,
                              hipStream_t stream) {
  const float* x    = (const float*)d_in[0];
  const float* cw   = (const float*)d_in[1];
  const float* cb   = (const float*)d_in[2];
  const float* g1   = (const float*)d_in[3];
  const float* b1v  = (const float*)d_in[4];
  const float* wihf = (const float*)d_in[5];
  const float* whhf = (const float*)d_in[6];
  const float* bihf = (const float*)d_in[7];
  const float* bhhf = (const float*)d_in[8];
  const float* wihb = (const float*)d_in[9];
  const float* whhb = (const float*)d_in[10];
  const float* bihb = (const float*)d_in[11];
  const float* bhhb = (const float*)d_in[12];
  const float* g2   = (const float*)d_in[13];
  const float* b2   = (const float*)d_in[14];
  const float* w1   = (const float*)d_in[15];
  const float* fb1  = (const float*)d_in[16];
  const float* g3   = (const float*)d_in[17];
  const float* b3   = (const float*)d_in[18];
  const float* w2   = (const float*)d_in[19];
  const float* fb2  = (const float*)d_in[20];
  float* out = (float*)d_out;

  uint8_t* base = (uint8_t*)d_ws;
  size_t off = 0;
  auto alloc = [&](size_t nfloats)->float*{
    float* p = (float*)(base + off);
    off = (off + nfloats*4 + 255) & ~(size_t)255;
    return p;
  };
  float* y      = alloc((size_t)B_*LOUT*NF);
  float* st     = alloc(256);
  float* wTf    = alloc((size_t)NF*NPAD);
  float* wTb    = alloc((size_t)NF*NPAD);
  float* bef    = alloc(NPAD);
  float* beb    = alloc(NPAD);
  float* hst    = alloc((size_t)2*B_*HID);
  float* cst    = alloc((size_t)2*B_*HID);
  float* mst    = alloc((size_t)2*B_*HID);
  float* pooled = alloc((size_t)B_*300);
  float* a2     = alloc(320);
  float* d2     = alloc(320);
  float* z1     = alloc((size_t)B_*50);
  float* a3     = alloc(64);
  float* d3     = alloc(64);
  size_t fixedEnd = off;

  int TC = 0;
  const int nchs[6] = {1,2,4,8,16,32};
  for (int ci=0; ci<6; ci++){
    int tcc = (LOUT + nchs[ci] - 1)/nchs[ci];
    size_t one = ((size_t)tcc*B_*NPAD*4 + 255) & ~(size_t)255;
    if (fixedEnd + 2*one <= ws_size){ TC = tcc; break; }
  }
  if (!TC) TC = 13;
  float* pref = alloc((size_t)TC*B_*NPAD);
  float* preb = alloc((size_t)TC*B_*NPAD);

  hipMemsetAsync(st, 0, 256*4, stream);
  k_conv<<<dim3((LOUT+3)/4, B_), 512, 0, stream>>>(x, cw, cb, y);
  k_stats1<<<256, 256, 0, stream>>>(y, st);
  k_prep<<<(2*NPAD+255)/256, 256, 0, stream>>>(st, g1, b1v, wihf, wihb,
                                               bihf, bhhf, bihb, bhhb,
                                               wTf, wTb, bef, beb);
  int t0 = 0; int first = 1;
  while (t0 < LOUT){
    int tc = (TC < LOUT - t0) ? TC : (LOUT - t0);
    int lastc = (t0 + tc >= LOUT) ? 1 : 0;
    k_proj<<<dim3(tc*8, 10), 256, 0, stream>>>(y, wTf, bef, pref, t0, +1, tc);
    k_proj<<<dim3(tc*8, 10), 256, 0, stream>>>(y, wTb, beb, preb, LOUT-1-t0, -1, tc);
    k_rec<<<256, 512, 0, stream>>>(whhf, whhb, pref, preb, hst, cst, mst,
                                   pooled, tc, first, lastc);
    t0 += tc; first = 0;
  }
  k_stats2<<<1, 320, 0, stream>>>(pooled, g2, b2, a2, d2);
  k_fc1<<<(B_*50+255)/256, 256, 0, stream>>>(pooled, a2, d2, w1, fb1, z1);
  k_stats3<<<1, 64, 0, stream>>>(z1, g3, b3, a3, d3);
  k_fc2<<<B_, 64, 0, stream>>>(z1, a3, d3, w2, fb2, out);
}

// Round 2
// 4011.884 us; speedup vs baseline: 1.9230x; 1.9230x over previous
//
#include <hip/hip_runtime.h>
#include <math.h>

#define B_   512
#define T_   800
#define FIN  3
#define NF   128
#define KW   15
#define HID  150
#define LOUT 393
#define G4   600
#define NPAD 640
#define EPS  1e-5f

__device__ __forceinline__ float hsig(float x){ return fminf(fmaxf(0.2f*x+0.5f,0.f),1.f); }
// NaN-safe fast tanh: exp(+inf)->1, exp(0)->-1
__device__ __forceinline__ float ftanh(float x){ float e=__expf(2.f*x); return 1.f - 2.f/(e+1.f); }

// ---------------- conv + relu + maxpool2 -> y[b][l][c] ----------------
__global__ __launch_bounds__(512) void k_conv(const float* __restrict__ x,
        const float* __restrict__ cw, const float* __restrict__ cb,
        float* __restrict__ y){
  __shared__ float wl[NF*FIN*KW];     // 5760
  __shared__ float xl[FIN][24];
  int tid = threadIdx.x;
  int b = blockIdx.y;
  int l0 = blockIdx.x*4;
  for (int i=tid;i<NF*FIN*KW;i+=512) wl[i]=cw[i];
  if (tid < FIN*22){ int f=tid/22, j=tid%22; int p = 2*l0+j;
     xl[f][j] = (p<T_)? x[(size_t)b*(FIN*T_) + (size_t)f*T_ + p] : 0.f; }
  __syncthreads();
  int c = tid & 127, li = tid >> 7;
  int l = l0 + li;
  if (l >= LOUT) return;
  float wr[FIN*KW];
  #pragma unroll
  for (int i=0;i<FIN*KW;i++) wr[i]=wl[c*FIN*KW+i];
  float xv[FIN][16];
  #pragma unroll
  for (int f=0;f<FIN;f++){
    #pragma unroll
    for (int j=0;j<16;j++) xv[f][j]=xl[f][2*li+j];
  }
  float a0=0.f,a1=0.f;
  #pragma unroll
  for (int f=0;f<FIN;f++){
    #pragma unroll
    for (int k=0;k<KW;k++){ float w=wr[f*KW+k]; a0 += w*xv[f][k]; a1 += w*xv[f][k+1]; }
  }
  float v = fmaxf(fmaxf(a0,a1)+cb[c], 0.f);
  y[((size_t)b*LOUT + l)*NF + c] = v;
}

// ---------------- per-channel stats over (b,l), vectorized ----------------
__global__ __launch_bounds__(256) void k_stats1(const float* __restrict__ y, float* __restrict__ st){
  __shared__ float ls[8][256];
  int tid = threadIdx.x;
  int row = tid >> 5, cg = tid & 31;
  for (int i=tid;i<8*256;i+=256) (&ls[0][0])[i]=0.f;
  __syncthreads();
  size_t N4 = (size_t)B_*LOUT*32;     // float4 count (128 ch = 32 float4)
  const float4* y4 = (const float4*)y;
  float s[4]={0,0,0,0}, q[4]={0,0,0,0};
  for (size_t i=(size_t)blockIdx.x*256+tid; i<N4; i+=(size_t)1024*256){
    float4 v=y4[i];
    s[0]+=v.x; q[0]+=v.x*v.x; s[1]+=v.y; q[1]+=v.y*v.y;
    s[2]+=v.z; q[2]+=v.z*v.z; s[3]+=v.w; q[3]+=v.w*v.w;
  }
  #pragma unroll
  for (int j=0;j<4;j++){ ls[row][cg*4+j]+=s[j]; ls[row][128+cg*4+j]+=q[j]; }
  __syncthreads();
  float tot=0.f;
  #pragma unroll
  for (int r=0;r<8;r++) tot += ls[r][tid];
  atomicAdd(&st[tid], tot);
}

// -------- fold AdaBN1 into projection weights: wT[f][n], bias_eff[n] --------
__global__ void k_prep(const float* __restrict__ st,
    const float* __restrict__ g1, const float* __restrict__ b1v,
    const float* __restrict__ wf, const float* __restrict__ wb,
    const float* __restrict__ bif, const float* __restrict__ bhf,
    const float* __restrict__ bib, const float* __restrict__ bhb,
    float* __restrict__ wTf, float* __restrict__ wTb,
    float* __restrict__ bef, float* __restrict__ beb){
  int id = blockIdx.x*256 + threadIdx.x;
  if (id >= 2*NPAD) return;
  int dir = id/NPAD, g = id%NPAD;
  float* wT = dir? wTb : wTf;
  float* be = dir? beb : bef;
  if (g >= G4){ for (int f=0;f<NF;f++) wT[(size_t)f*NPAD+g]=0.f; be[g]=0.f; return; }
  const float* wih = dir? wb : wf;
  float bias = dir? (bib[g]+bhb[g]) : (bif[g]+bhf[g]);
  const float Ninv = 1.f/((float)B_*(float)LOUT);
  for (int f=0;f<NF;f++){
    float m = st[f]*Ninv;
    float var = st[NF+f]*Ninv - m*m;
    float a = g1[f]*rsqrtf(var+EPS);
    float d = b1v[f] - m*a;
    float w = wih[g*NF+f];
    wT[(size_t)f*NPAD+g] = a*w;
    bias += d*w;
  }
  be[g] = bias;
}

// ---------------- projection GEMM: pre[trel*512+b][n] = y[b][t].wT + be ----------------
// 128x128 tile, 256 threads, 8x8 acc, one-shot K=128, both dirs via blockIdx.z
__global__ __launch_bounds__(256, 2) void k_proj(const float* __restrict__ y,
    const float* __restrict__ wTf, const float* __restrict__ wTb,
    const float* __restrict__ bef, const float* __restrict__ beb,
    float* __restrict__ pref, float* __restrict__ preb,
    int t0f, int tc){
  __shared__ float As[128*128];   // k-major: As[k*128 + m]
  __shared__ float Bs[128*132];   // Bs[k*132 + n] (pad 4 to break write conflicts)
  int dir = blockIdx.z;
  const float* wT = dir? wTb : wTf;
  const float* be = dir? beb : bef;
  float* pre = dir? preb : pref;
  int tid = threadIdx.x;
  int m0 = blockIdx.x*128, n0 = blockIdx.y*128;
  int trel = m0>>9, bb = m0&511;
  int t = dir ? (LOUT-1-t0f-trel) : (t0f+trel);
  {
    int r = tid>>1, half = tid&1;
    const float* arow = y + ((size_t)(bb+r)*LOUT + t)*NF + half*64;
    #pragma unroll
    for (int q=0;q<16;q++){
      float4 v = *(const float4*)(arow + q*4);
      int c = half*64 + q*4;
      As[(c+0)*128+r]=v.x; As[(c+1)*128+r]=v.y; As[(c+2)*128+r]=v.z; As[(c+3)*128+r]=v.w;
    }
    const float* brow = wT + (size_t)r*NPAD + n0 + half*64;
    #pragma unroll
    for (int q=0;q<16;q++)
      *(float4*)&Bs[r*132 + half*64 + q*4] = *(const float4*)(brow + q*4);
  }
  __syncthreads();
  int lane = tid & 63, wv = tid>>6;
  int mi = ((lane&3) + wv*4)*8;   // A-read: 4 addrs/wave, 16-lane broadcast
  int ni = (lane>>2)*8;
  float acc[8][8];
  #pragma unroll
  for (int i=0;i<8;i++)
    #pragma unroll
    for (int j=0;j<8;j++) acc[i][j]=0.f;
  #pragma unroll 2
  for (int k=0;k<128;k++){
    float4 a0=*(const float4*)&As[k*128+mi], a1=*(const float4*)&As[k*128+mi+4];
    float4 b0=*(const float4*)&Bs[k*132+ni], b1=*(const float4*)&Bs[k*132+ni+4];
    float av[8]={a0.x,a0.y,a0.z,a0.w,a1.x,a1.y,a1.z,a1.w};
    float bv[8]={b0.x,b0.y,b0.z,b0.w,b1.x,b1.y,b1.z,b1.w};
    #pragma unroll
    for (int i=0;i<8;i++)
      #pragma unroll
      for (int j=0;j<8;j++) acc[i][j] += av[i]*bv[j];
  }
  float4 bl0=*(const float4*)&be[n0+ni], bl1=*(const float4*)&be[n0+ni+4];
  float bv[8]={bl0.x,bl0.y,bl0.z,bl0.w,bl1.x,bl1.y,bl1.z,bl1.w};
  #pragma unroll
  for (int i=0;i<8;i++){
    float* dst = pre + (size_t)(m0+mi+i)*NPAD + n0 + ni;
    float4 o0={acc[i][0]+bv[0],acc[i][1]+bv[1],acc[i][2]+bv[2],acc[i][3]+bv[3]};
    float4 o1={acc[i][4]+bv[4],acc[i][5]+bv[5],acc[i][6]+bv[6],acc[i][7]+bv[7]};
    *(float4*)dst = o0; *(float4*)(dst+4) = o1;
  }
}

// ---------------- recurrence: register-resident w_hh (no spill), fused time-max ----------------
__global__ __launch_bounds__(512, 2) void k_rec(const float* __restrict__ whf,
    const float* __restrict__ whb,
    const float* __restrict__ pref, const float* __restrict__ preb,
    float* __restrict__ hst, float* __restrict__ cst, float* __restrict__ mst,
    float* __restrict__ pooled, int tc, int first, int last){
  int dir = blockIdx.x >> 7;
  int b0 = (blockIdx.x & 127)*4;
  const float* wh  = dir? whb : whf;
  const float* pre = dir? preb : pref;
  int tid = threadIdx.x;
  int lane = tid & 63, wv = tid >> 6;
  int gl = lane & 15, kl = lane >> 4;
  int glc = (gl<15)? gl : 14;          // clamp lane 15 -> duplicate work, writes masked
  int gbase = wv*75 + glc*5;
  int kq = kl*38;                       // 4x38 = 152 covers 150 (+2 zero pad)

  __shared__ float hls[4][160];         // h state, zero-padded 150..159
  __shared__ float dls[4][608];         // gate matvec results
  __shared__ float pls[2][4][608];      // pre double buffer

  // weights -> registers, direct global loads (L2-broadcast across blocks)
  float w[5][38];
  #pragma unroll
  for (int i=0;i<5;i++){
    const float* wrow = wh + (size_t)(gbase+i)*HID + kq;
    #pragma unroll
    for (int j=0;j<38;j++) w[i][j] = (kq+j < HID)? wrow[j] : 0.f;
  }

  int u1 = tid % 150, b1 = tid / 150;
  int u2 = (tid+512) % 150, b2 = (tid+512) / 150;
  bool has2 = tid < 88;
  float cr0, cr1=0.f, mr0, mr1=-1e30f;
  if (first){
    cr0=0.f; mr0=-1e30f;
    for (int i=tid;i<4*160;i+=512) (&hls[0][0])[i]=0.f;
  } else {
    cr0 = cst[((size_t)dir*B_ + b0+b1)*HID + u1];
    mr0 = mst[((size_t)dir*B_ + b0+b1)*HID + u1];
    if (has2){
      cr1 = cst[((size_t)dir*B_ + b0+b2)*HID + u2];
      mr1 = mst[((size_t)dir*B_ + b0+b2)*HID + u2];
    }
    for (int i=tid;i<4*160;i+=512){ int bq=i/160, uu=i%160;
      (&hls[0][0])[i] = (uu<HID)? hst[((size_t)dir*B_ + b0+bq)*HID+uu] : 0.f; }
  }
  // preload pre[t=0] (4 rows x 608 floats = 1216 float2)
  for (int j=tid;j<1216;j+=512){ int r=j/304, cc=j%304;
    ((float2*)&pls[0][r][0])[cc] =
      ((const float2*)(pre + (size_t)(b0+r)*NPAD))[cc];
  }
  __syncthreads();

  int cur=0;
  for (int t=0;t<tc;t++){
    // prefetch next pre -> regs
    float2 pfa, pfb, pfc;
    bool ld = (t+1 < tc), l3 = tid < 192;
    if (ld){
      size_t base = (size_t)(t+1)*B_ + b0;
      { int j=tid;      int r=j/304, cc=j%304; pfa = ((const float2*)(pre + (base+r)*NPAD))[cc]; }
      { int j=tid+512;  int r=j/304, cc=j%304; pfb = ((const float2*)(pre + (base+r)*NPAD))[cc]; }
      if (l3){ int j=tid+1024; int r=j/304, cc=j%304; pfc = ((const float2*)(pre + (base+r)*NPAD))[cc]; }
    }
    // matvec: batches 0,1
    {
      const float2* h0 = (const float2*)&hls[0][kq];
      const float2* h1 = (const float2*)&hls[1][kq];
      float acc[5][2];
      #pragma unroll
      for (int i=0;i<5;i++){acc[i][0]=0.f;acc[i][1]=0.f;}
      #pragma unroll
      for (int p=0;p<19;p++){
        float2 ha=h0[p], hb=h1[p];
        #pragma unroll
        for (int i=0;i<5;i++){
          acc[i][0] += w[i][2*p]*ha.x + w[i][2*p+1]*ha.y;
          acc[i][1] += w[i][2*p]*hb.x + w[i][2*p+1]*hb.y;
        }
      }
      #pragma unroll
      for (int i=0;i<5;i++){
        acc[i][0] += __shfl_xor(acc[i][0],16); acc[i][0] += __shfl_xor(acc[i][0],32);
        acc[i][1] += __shfl_xor(acc[i][1],16); acc[i][1] += __shfl_xor(acc[i][1],32);
      }
      if (kl==0 && gl<15){
        #pragma unroll
        for (int i=0;i<5;i++){ dls[0][gbase+i]=acc[i][0]; dls[1][gbase+i]=acc[i][1]; }
      }
    }
    // matvec: batches 2,3
    {
      const float2* h2 = (const float2*)&hls[2][kq];
      const float2* h3 = (const float2*)&hls[3][kq];
      float acc[5][2];
      #pragma unroll
      for (int i=0;i<5;i++){acc[i][0]=0.f;acc[i][1]=0.f;}
      #pragma unroll
      for (int p=0;p<19;p++){
        float2 ha=h2[p], hb=h3[p];
        #pragma unroll
        for (int i=0;i<5;i++){
          acc[i][0] += w[i][2*p]*ha.x + w[i][2*p+1]*ha.y;
          acc[i][1] += w[i][2*p]*hb.x + w[i][2*p+1]*hb.y;
        }
      }
      #pragma unroll
      for (int i=0;i<5;i++){
        acc[i][0] += __shfl_xor(acc[i][0],16); acc[i][0] += __shfl_xor(acc[i][0],32);
        acc[i][1] += __shfl_xor(acc[i][1],16); acc[i][1] += __shfl_xor(acc[i][1],32);
      }
      if (kl==0 && gl<15){
        #pragma unroll
        for (int i=0;i<5;i++){ dls[2][gbase+i]=acc[i][0]; dls[3][gbase+i]=acc[i][1]; }
      }
    }
    __syncthreads();
    // gates, cell update, running max  (unit (b1,u1) per thread, +88 extras)
    {
      float pi = dls[b1][u1]      + pls[cur][b1][u1];
      float pf = dls[b1][150+u1]  + pls[cur][b1][150+u1];
      float pg = dls[b1][300+u1]  + pls[cur][b1][300+u1];
      float po = dls[b1][450+u1]  + pls[cur][b1][450+u1];
      float ig=hsig(pi), fg=hsig(pf), og=hsig(po), gg=ftanh(pg);
      cr0 = fg*cr0 + ig*gg;
      float hv = og*ftanh(cr0);
      mr0 = fmaxf(mr0,hv);
      hls[b1][u1] = hv;
      if (has2){
        float pi2 = dls[b2][u2]      + pls[cur][b2][u2];
        float pf2 = dls[b2][150+u2]  + pls[cur][b2][150+u2];
        float pg2 = dls[b2][300+u2]  + pls[cur][b2][300+u2];
        float po2 = dls[b2][450+u2]  + pls[cur][b2][450+u2];
        float ig2=hsig(pi2), fg2=hsig(pf2), og2=hsig(po2), gg2=ftanh(pg2);
        cr1 = fg2*cr1 + ig2*gg2;
        float hv2 = og2*ftanh(cr1);
        mr1 = fmaxf(mr1,hv2);
        hls[b2][u2] = hv2;
      }
    }
    if (ld){
      int nx = cur^1;
      { int j=tid;      int r=j/304, cc=j%304; ((float2*)&pls[nx][r][0])[cc]=pfa; }
      { int j=tid+512;  int r=j/304, cc=j%304; ((float2*)&pls[nx][r][0])[cc]=pfb; }
      if (l3){ int j=tid+1024; int r=j/304, cc=j%304; ((float2*)&pls[nx][r][0])[cc]=pfc; }
    }
    __syncthreads();
    cur ^= 1;
  }
  hst[((size_t)dir*B_ + b0+b1)*HID+u1] = hls[b1][u1];
  cst[((size_t)dir*B_ + b0+b1)*HID+u1] = cr0;
  mst[((size_t)dir*B_ + b0+b1)*HID+u1] = mr0;
  if (has2){
    hst[((size_t)dir*B_ + b0+b2)*HID+u2] = hls[b2][u2];
    cst[((size_t)dir*B_ + b0+b2)*HID+u2] = cr1;
    mst[((size_t)dir*B_ + b0+b2)*HID+u2] = mr1;
  }
  if (last){
    pooled[(size_t)(b0+b1)*300 + dir*HID + u1] = mr0;
    if (has2) pooled[(size_t)(b0+b2)*300 + dir*HID + u2] = mr1;
  }
}

// ---------------- tail: AdaBN2 stats ----------------
__global__ void k_stats2(const float* __restrict__ pooled,
    const float* __restrict__ g2, const float* __restrict__ b2,
    float* __restrict__ a2, float* __restrict__ d2){
  int f = threadIdx.x;
  if (f >= 300) return;
  float s=0.f,q=0.f;
  for (int b=0;b<B_;b++){ float v = pooled[(size_t)b*300+f]; s+=v; q+=v*v; }
  float m = s*(1.f/B_), var = q*(1.f/B_) - m*m;
  float a = g2[f]*rsqrtf(var+EPS);
  a2[f]=a; d2[f]=b2[f]-m*a;
}

// ---------------- fc1 (+folded AdaBN2) + relu ----------------
__global__ void k_fc1(const float* __restrict__ pooled,
    const float* __restrict__ a2, const float* __restrict__ d2,
    const float* __restrict__ w1, const float* __restrict__ fb1,
    float* __restrict__ z1){
  int o = blockIdx.x*256 + threadIdx.x;
  if (o >= B_*50) return;
  int b = o/50, j = o%50;
  float acc = fb1[j];
  for (int f=0;f<300;f++)
    acc += (a2[f]*pooled[(size_t)b*300+f] + d2[f]) * w1[j*300+f];
  z1[o] = fmaxf(acc,0.f);
}

// ---------------- AdaBN3 stats ----------------
__global__ void k_stats3(const float* __restrict__ z1,
    const float* __restrict__ g3, const float* __restrict__ b3,
    float* __restrict__ a3, float* __restrict__ d3){
  int f = threadIdx.x;
  if (f >= 50) return;
  float s=0.f,q=0.f;
  for (int b=0;b<B_;b++){ float v = z1[(size_t)b*50+f]; s+=v; q+=v*v; }
  float m = s*(1.f/B_), var = q*(1.f/B_) - m*m;
  float a = g3[f]*rsqrtf(var+EPS);
  a3[f]=a; d3[f]=b3[f]-m*a;
}

// ---------------- fc2 (+folded AdaBN3) + softmax ----------------
__global__ void k_fc2(const float* __restrict__ z1,
    const float* __restrict__ a3, const float* __restrict__ d3,
    const float* __restrict__ w2, const float* __restrict__ fb2,
    float* __restrict__ out){
  int b = blockIdx.x;
  int t = threadIdx.x;
  __shared__ float zl[50];
  __shared__ float lg[10];
  if (t<50) zl[t] = a3[t]*z1[(size_t)b*50+t] + d3[t];
  __syncthreads();
  if (t<10){
    float acc = fb2[t];
    for (int j=0;j<50;j++) acc += zl[j]*w2[t*50+j];
    lg[t]=acc;
  }
  __syncthreads();
  if (t<10){
    float m = lg[0];
    #pragma unroll
    for (int i=1;i<10;i++) m = fmaxf(m,lg[i]);
    float s = 0.f;
    #pragma unroll
    for (int i=0;i<10;i++) s += expf(lg[i]-m);
    out[(size_t)b*10+t] = expf(lg[t]-m)/s;
  }
}

extern "C" void kernel_launch(void* const* d_in, const int* in_sizes, int n_in,
                              void* d_out, int out_size, void* d_ws, size_t ws_size,
                              hipStream_t stream) {
  const float* x    = (const float*)d_in[0];
  const float* cw   = (const float*)d_in[1];
  const float* cb   = (const float*)d_in[2];
  const float* g1   = (const float*)d_in[3];
  const float* b1v  = (const float*)d_in[4];
  const float* wihf = (const float*)d_in[5];
  const float* whhf = (const float*)d_in[6];
  const float* bihf = (const float*)d_in[7];
  const float* bhhf = (const float*)d_in[8];
  const float* wihb = (const float*)d_in[9];
  const float* whhb = (const float*)d_in[10];
  const float* bihb = (const float*)d_in[11];
  const float* bhhb = (const float*)d_in[12];
  const float* g2   = (const float*)d_in[13];
  const float* b2   = (const float*)d_in[14];
  const float* w1   = (const float*)d_in[15];
  const float* fb1  = (const float*)d_in[16];
  const float* g3   = (const float*)d_in[17];
  const float* b3   = (const float*)d_in[18];
  const float* w2   = (const float*)d_in[19];
  const float* fb2  = (const float*)d_in[20];
  float* out = (float*)d_out;

  uint8_t* base = (uint8_t*)d_ws;
  size_t off = 0;
  auto alloc = [&](size_t nfloats)->float*{
    float* p = (float*)(base + off);
    off = (off + nfloats*4 + 255) & ~(size_t)255;
    return p;
  };
  float* y      = alloc((size_t)B_*LOUT*NF);
  float* st     = alloc(256);
  float* wTf    = alloc((size_t)NF*NPAD);
  float* wTb    = alloc((size_t)NF*NPAD);
  float* bef    = alloc(NPAD);
  float* beb    = alloc(NPAD);
  float* hst    = alloc((size_t)2*B_*HID);
  float* cst    = alloc((size_t)2*B_*HID);
  float* mst    = alloc((size_t)2*B_*HID);
  float* pooled = alloc((size_t)B_*300);
  float* a2     = alloc(320);
  float* d2     = alloc(320);
  float* z1     = alloc((size_t)B_*50);
  float* a3     = alloc(64);
  float* d3     = alloc(64);
  size_t fixedEnd = off;

  // largest tc whose double pre-buffers fit, then equalize chunk sizes
  size_t per_t = (size_t)2*B_*NPAD*4;   // both directions, per timestep
  size_t avail = (ws_size > fixedEnd + 4096) ? (ws_size - fixedEnd - 4096) : 0;
  int tcmax = (int)(avail / per_t);
  if (tcmax < 1) tcmax = 1;
  if (tcmax > LOUT) tcmax = LOUT;
  int nch = (LOUT + tcmax - 1) / tcmax;
  int TC = (LOUT + nch - 1) / nch;
  float* pref = alloc((size_t)TC*B_*NPAD);
  float* preb = alloc((size_t)TC*B_*NPAD);

  hipMemsetAsync(st, 0, 256*4, stream);
  k_conv<<<dim3((LOUT+3)/4, B_), 512, 0, stream>>>(x, cw, cb, y);
  k_stats1<<<1024, 256, 0, stream>>>(y, st);
  k_prep<<<(2*NPAD+255)/256, 256, 0, stream>>>(st, g1, b1v, wihf, wihb,
                                               bihf, bhhf, bihb, bhhb,
                                               wTf, wTb, bef, beb);
  int t0 = 0; int first = 1;
  while (t0 < LOUT){
    int tc = (TC < LOUT - t0) ? TC : (LOUT - t0);
    int lastc = (t0 + tc >= LOUT) ? 1 : 0;
    k_proj<<<dim3(tc*4, 5, 2), 256, 0, stream>>>(y, wTf, wTb, bef, beb,
                                                 pref, preb, t0, tc);
    k_rec<<<256, 512, 0, stream>>>(whhf, whhb, pref, preb, hst, cst, mst,
                                   pooled, tc, first, lastc);
    t0 += tc; first = 0;
  }
  k_stats2<<<1, 320, 0, stream>>>(pooled, g2, b2, a2, d2);
  k_fc1<<<(B_*50+255)/256, 256, 0, stream>>>(pooled, a2, d2, w1, fb1, z1);
  k_stats3<<<1, 64, 0, stream>>>(z1, g3, b3, a3, d3);
  k_fc2<<<B_, 64, 0, stream>>>(z1, a3, d3, w2, fb2, out);
}

// Round 3
// 3489.516 us; speedup vs baseline: 2.2109x; 1.1497x over previous
//
#include <hip/hip_runtime.h>
#include <math.h>

#define B_   512
#define T_   800
#define FIN  3
#define NF   128
#define KW   15
#define HID  150
#define LOUT 393
#define G4   600
#define NPAD 640
#define EPS  1e-5f

__device__ __forceinline__ float hsig(float x){ return fminf(fmaxf(0.2f*x+0.5f,0.f),1.f); }
// NaN-safe fast tanh: exp(+inf)->1, exp(0)->-1
__device__ __forceinline__ float ftanh(float x){ float e=__expf(2.f*x); return 1.f - 2.f/(e+1.f); }

// ---------------- conv + relu + maxpool2 -> y[b][l][c] ----------------
__global__ __launch_bounds__(512) void k_conv(const float* __restrict__ x,
        const float* __restrict__ cw, const float* __restrict__ cb,
        float* __restrict__ y){
  __shared__ float wl[NF*FIN*KW];     // 5760
  __shared__ float xl[FIN][24];
  int tid = threadIdx.x;
  int b = blockIdx.y;
  int l0 = blockIdx.x*4;
  for (int i=tid;i<NF*FIN*KW;i+=512) wl[i]=cw[i];
  if (tid < FIN*22){ int f=tid/22, j=tid%22; int p = 2*l0+j;
     xl[f][j] = (p<T_)? x[(size_t)b*(FIN*T_) + (size_t)f*T_ + p] : 0.f; }
  __syncthreads();
  int c = tid & 127, li = tid >> 7;
  int l = l0 + li;
  if (l >= LOUT) return;
  float wr[FIN*KW];
  #pragma unroll
  for (int i=0;i<FIN*KW;i++) wr[i]=wl[c*FIN*KW+i];
  float xv[FIN][16];
  #pragma unroll
  for (int f=0;f<FIN;f++){
    #pragma unroll
    for (int j=0;j<16;j++) xv[f][j]=xl[f][2*li+j];
  }
  float a0=0.f,a1=0.f;
  #pragma unroll
  for (int f=0;f<FIN;f++){
    #pragma unroll
    for (int k=0;k<KW;k++){ float w=wr[f*KW+k]; a0 += w*xv[f][k]; a1 += w*xv[f][k+1]; }
  }
  float v = fmaxf(fmaxf(a0,a1)+cb[c], 0.f);
  y[((size_t)b*LOUT + l)*NF + c] = v;
}

// ---------------- per-channel stats over (b,l), vectorized ----------------
__global__ __launch_bounds__(256) void k_stats1(const float* __restrict__ y, float* __restrict__ st){
  __shared__ float ls[8][256];
  int tid = threadIdx.x;
  int row = tid >> 5, cg = tid & 31;
  for (int i=tid;i<8*256;i+=256) (&ls[0][0])[i]=0.f;
  __syncthreads();
  size_t N4 = (size_t)B_*LOUT*32;     // float4 count (128 ch = 32 float4)
  const float4* y4 = (const float4*)y;
  float s[4]={0,0,0,0}, q[4]={0,0,0,0};
  for (size_t i=(size_t)blockIdx.x*256+tid; i<N4; i+=(size_t)1024*256){
    float4 v=y4[i];
    s[0]+=v.x; q[0]+=v.x*v.x; s[1]+=v.y; q[1]+=v.y*v.y;
    s[2]+=v.z; q[2]+=v.z*v.z; s[3]+=v.w; q[3]+=v.w*v.w;
  }
  #pragma unroll
  for (int j=0;j<4;j++){ ls[row][cg*4+j]+=s[j]; ls[row][128+cg*4+j]+=q[j]; }
  __syncthreads();
  float tot=0.f;
  #pragma unroll
  for (int r=0;r<8;r++) tot += ls[r][tid];
  atomicAdd(&st[tid], tot);
}

// -------- fold AdaBN1 into projection weights: wT[f][n], bias_eff[n] --------
__global__ void k_prep(const float* __restrict__ st,
    const float* __restrict__ g1, const float* __restrict__ b1v,
    const float* __restrict__ wf, const float* __restrict__ wb,
    const float* __restrict__ bif, const float* __restrict__ bhf,
    const float* __restrict__ bib, const float* __restrict__ bhb,
    float* __restrict__ wTf, float* __restrict__ wTb,
    float* __restrict__ bef, float* __restrict__ beb){
  int id = blockIdx.x*256 + threadIdx.x;
  if (id >= 2*NPAD) return;
  int dir = id/NPAD, g = id%NPAD;
  float* wT = dir? wTb : wTf;
  float* be = dir? beb : bef;
  if (g >= G4){ for (int f=0;f<NF;f++) wT[(size_t)f*NPAD+g]=0.f; be[g]=0.f; return; }
  const float* wih = dir? wb : wf;
  float bias = dir? (bib[g]+bhb[g]) : (bif[g]+bhf[g]);
  const float Ninv = 1.f/((float)B_*(float)LOUT);
  for (int f=0;f<NF;f++){
    float m = st[f]*Ninv;
    float var = st[NF+f]*Ninv - m*m;
    float a = g1[f]*rsqrtf(var+EPS);
    float d = b1v[f] - m*a;
    float w = wih[g*NF+f];
    wT[(size_t)f*NPAD+g] = a*w;
    bias += d*w;
  }
  be[g] = bias;
}

// ---------------- projection GEMM: pre[trel*512+b][n] = y[b][t].wT + be ----------------
// 128x128 tile, 256 threads, 8x8 acc, K tiled by 64 (66KB LDS -> 2 blocks/CU)
__global__ __launch_bounds__(256, 2) void k_proj(const float* __restrict__ y,
    const float* __restrict__ wTf, const float* __restrict__ wTb,
    const float* __restrict__ bef, const float* __restrict__ beb,
    float* __restrict__ pref, float* __restrict__ preb,
    int t0f, int tc){
  __shared__ float As[64*132];   // k-major: As[k*132 + m]
  __shared__ float Bs[64*132];   // Bs[k*132 + n]
  int dir = blockIdx.z;
  const float* wT = dir? wTb : wTf;
  const float* be = dir? beb : bef;
  float* pre = dir? preb : pref;
  int tid = threadIdx.x;
  int m0 = blockIdx.x*128, n0 = blockIdx.y*128;
  int trel = m0>>9, bb = m0&511;
  int t = dir ? (LOUT-1-t0f-trel) : (t0f+trel);
  int lane = tid & 63, wv = tid>>6;
  int mi = ((lane&3) + wv*4)*8;   // A-read: 4 addrs/wave, 16-lane broadcast
  int ni = (lane>>2)*8;
  int ar = tid>>1, ah = tid&1;    // A stage: row, which 32-k half
  int bk = tid>>5, bn = (tid&31)*4; // B stage: k row base, n col (float4)
  float acc[8][8];
  #pragma unroll
  for (int i=0;i<8;i++)
    #pragma unroll
    for (int j=0;j<8;j++) acc[i][j]=0.f;

  const float* arow = y + ((size_t)(bb+ar)*LOUT + t)*NF + ah*32;
  #pragma unroll
  for (int kt=0; kt<2; kt++){
    if (kt) __syncthreads();
    #pragma unroll
    for (int q=0;q<8;q++){
      float4 v = *(const float4*)(arow + kt*64 + q*4);
      int kk = ah*32 + q*4;
      As[(kk+0)*132+ar]=v.x; As[(kk+1)*132+ar]=v.y; As[(kk+2)*132+ar]=v.z; As[(kk+3)*132+ar]=v.w;
    }
    #pragma unroll
    for (int j=0;j<8;j++){
      int kk = bk + j*8;
      *(float4*)&Bs[kk*132 + bn] = *(const float4*)&wT[(size_t)(kt*64+kk)*NPAD + n0 + bn];
    }
    __syncthreads();
    #pragma unroll 4
    for (int k=0;k<64;k++){
      float4 a0=*(const float4*)&As[k*132+mi], a1=*(const float4*)&As[k*132+mi+4];
      float4 b0=*(const float4*)&Bs[k*132+ni], b1=*(const float4*)&Bs[k*132+ni+4];
      float av[8]={a0.x,a0.y,a0.z,a0.w,a1.x,a1.y,a1.z,a1.w};
      float bv[8]={b0.x,b0.y,b0.z,b0.w,b1.x,b1.y,b1.z,b1.w};
      #pragma unroll
      for (int i=0;i<8;i++)
        #pragma unroll
        for (int j=0;j<8;j++) acc[i][j] += av[i]*bv[j];
    }
  }
  float4 bl0=*(const float4*)&be[n0+ni], bl1=*(const float4*)&be[n0+ni+4];
  float bv[8]={bl0.x,bl0.y,bl0.z,bl0.w,bl1.x,bl1.y,bl1.z,bl1.w};
  #pragma unroll
  for (int i=0;i<8;i++){
    float* dst = pre + (size_t)(m0+mi+i)*NPAD + n0 + ni;
    float4 o0={acc[i][0]+bv[0],acc[i][1]+bv[1],acc[i][2]+bv[2],acc[i][3]+bv[3]};
    float4 o1={acc[i][4]+bv[4],acc[i][5]+bv[5],acc[i][6]+bv[6],acc[i][7]+bv[7]};
    *(float4*)dst = o0; *(float4*)(dst+4) = o1;
  }
}

// ---------------- recurrence: register-resident w_hh (no spill), fused time-max ----------------
// __launch_bounds__(512,1): 1 block/CU -> VGPR cap 256, w[5][38]=190 stays in regs
__global__ __launch_bounds__(512, 1) void k_rec(const float* __restrict__ whf,
    const float* __restrict__ whb,
    const float* __restrict__ pref, const float* __restrict__ preb,
    float* __restrict__ hst, float* __restrict__ cst, float* __restrict__ mst,
    float* __restrict__ pooled, int tc, int first, int last){
  int dir = blockIdx.x >> 7;
  int b0 = (blockIdx.x & 127)*4;
  const float* wh  = dir? whb : whf;
  const float* pre = dir? preb : pref;
  int tid = threadIdx.x;
  int lane = tid & 63, wv = tid >> 6;
  int gl = lane & 15, kl = lane >> 4;
  int glc = (gl<15)? gl : 14;          // clamp lane 15 -> duplicate work, writes masked
  int gbase = wv*75 + glc*5;
  int kq = kl*38;                       // 4x38 = 152 covers 150 (+2 zero pad)

  __shared__ float hls[4][160];         // h state, zero-padded 150..159
  __shared__ float dls[4][608];         // gate matvec results
  __shared__ float pls[2][4][608];      // pre double buffer

  // weights -> registers, direct global loads (L2/L3-broadcast across blocks)
  float w[5][38];
  #pragma unroll
  for (int i=0;i<5;i++){
    const float* wrow = wh + (size_t)(gbase+i)*HID + kq;
    #pragma unroll
    for (int j=0;j<38;j++) w[i][j] = (kq+j < HID)? wrow[j] : 0.f;
  }

  int u1 = tid % 150, b1 = tid / 150;
  int u2 = (tid+512) % 150, b2 = (tid+512) / 150;
  bool has2 = tid < 88;
  float cr0, cr1=0.f, mr0, mr1=-1e30f;
  if (first){
    cr0=0.f; mr0=-1e30f;
    for (int i=tid;i<4*160;i+=512) (&hls[0][0])[i]=0.f;
  } else {
    cr0 = cst[((size_t)dir*B_ + b0+b1)*HID + u1];
    mr0 = mst[((size_t)dir*B_ + b0+b1)*HID + u1];
    if (has2){
      cr1 = cst[((size_t)dir*B_ + b0+b2)*HID + u2];
      mr1 = mst[((size_t)dir*B_ + b0+b2)*HID + u2];
    }
    for (int i=tid;i<4*160;i+=512){ int bq=i/160, uu=i%160;
      (&hls[0][0])[i] = (uu<HID)? hst[((size_t)dir*B_ + b0+bq)*HID+uu] : 0.f; }
  }
  // preload pre[t=0] (4 rows x 608 floats = 1216 float2)
  for (int j=tid;j<1216;j+=512){ int r=j/304, cc=j%304;
    ((float2*)&pls[0][r][0])[cc] =
      ((const float2*)(pre + (size_t)(b0+r)*NPAD))[cc];
  }
  __syncthreads();

  int cur=0;
  for (int t=0;t<tc;t++){
    // prefetch next pre -> regs
    float2 pfa, pfb, pfc;
    bool ld = (t+1 < tc), l3 = tid < 192;
    if (ld){
      size_t base = (size_t)(t+1)*B_ + b0;
      { int j=tid;      int r=j/304, cc=j%304; pfa = ((const float2*)(pre + (base+r)*NPAD))[cc]; }
      { int j=tid+512;  int r=j/304, cc=j%304; pfb = ((const float2*)(pre + (base+r)*NPAD))[cc]; }
      if (l3){ int j=tid+1024; int r=j/304, cc=j%304; pfc = ((const float2*)(pre + (base+r)*NPAD))[cc]; }
    }
    // matvec: batches 0,1
    {
      const float2* h0 = (const float2*)&hls[0][kq];
      const float2* h1 = (const float2*)&hls[1][kq];
      float acc[5][2];
      #pragma unroll
      for (int i=0;i<5;i++){acc[i][0]=0.f;acc[i][1]=0.f;}
      #pragma unroll
      for (int p=0;p<19;p++){
        float2 ha=h0[p], hb=h1[p];
        #pragma unroll
        for (int i=0;i<5;i++){
          acc[i][0] += w[i][2*p]*ha.x + w[i][2*p+1]*ha.y;
          acc[i][1] += w[i][2*p]*hb.x + w[i][2*p+1]*hb.y;
        }
      }
      #pragma unroll
      for (int i=0;i<5;i++){
        acc[i][0] += __shfl_xor(acc[i][0],16); acc[i][0] += __shfl_xor(acc[i][0],32);
        acc[i][1] += __shfl_xor(acc[i][1],16); acc[i][1] += __shfl_xor(acc[i][1],32);
      }
      if (kl==0 && gl<15){
        #pragma unroll
        for (int i=0;i<5;i++){ dls[0][gbase+i]=acc[i][0]; dls[1][gbase+i]=acc[i][1]; }
      }
    }
    // matvec: batches 2,3
    {
      const float2* h2 = (const float2*)&hls[2][kq];
      const float2* h3 = (const float2*)&hls[3][kq];
      float acc[5][2];
      #pragma unroll
      for (int i=0;i<5;i++){acc[i][0]=0.f;acc[i][1]=0.f;}
      #pragma unroll
      for (int p=0;p<19;p++){
        float2 ha=h2[p], hb=h3[p];
        #pragma unroll
        for (int i=0;i<5;i++){
          acc[i][0] += w[i][2*p]*ha.x + w[i][2*p+1]*ha.y;
          acc[i][1] += w[i][2*p]*hb.x + w[i][2*p+1]*hb.y;
        }
      }
      #pragma unroll
      for (int i=0;i<5;i++){
        acc[i][0] += __shfl_xor(acc[i][0],16); acc[i][0] += __shfl_xor(acc[i][0],32);
        acc[i][1] += __shfl_xor(acc[i][1],16); acc[i][1] += __shfl_xor(acc[i][1],32);
      }
      if (kl==0 && gl<15){
        #pragma unroll
        for (int i=0;i<5;i++){ dls[2][gbase+i]=acc[i][0]; dls[3][gbase+i]=acc[i][1]; }
      }
    }
    __syncthreads();
    // gates, cell update, running max  (unit (b1,u1) per thread, +88 extras)
    {
      float pi = dls[b1][u1]      + pls[cur][b1][u1];
      float pf = dls[b1][150+u1]  + pls[cur][b1][150+u1];
      float pg = dls[b1][300+u1]  + pls[cur][b1][300+u1];
      float po = dls[b1][450+u1]  + pls[cur][b1][450+u1];
      float ig=hsig(pi), fg=hsig(pf), og=hsig(po), gg=ftanh(pg);
      cr0 = fg*cr0 + ig*gg;
      float hv = og*ftanh(cr0);
      mr0 = fmaxf(mr0,hv);
      hls[b1][u1] = hv;
      if (has2){
        float pi2 = dls[b2][u2]      + pls[cur][b2][u2];
        float pf2 = dls[b2][150+u2]  + pls[cur][b2][150+u2];
        float pg2 = dls[b2][300+u2]  + pls[cur][b2][300+u2];
        float po2 = dls[b2][450+u2]  + pls[cur][b2][450+u2];
        float ig2=hsig(pi2), fg2=hsig(pf2), og2=hsig(po2), gg2=ftanh(pg2);
        cr1 = fg2*cr1 + ig2*gg2;
        float hv2 = og2*ftanh(cr1);
        mr1 = fmaxf(mr1,hv2);
        hls[b2][u2] = hv2;
      }
    }
    if (ld){
      int nx = cur^1;
      { int j=tid;      int r=j/304, cc=j%304; ((float2*)&pls[nx][r][0])[cc]=pfa; }
      { int j=tid+512;  int r=j/304, cc=j%304; ((float2*)&pls[nx][r][0])[cc]=pfb; }
      if (l3){ int j=tid+1024; int r=j/304, cc=j%304; ((float2*)&pls[nx][r][0])[cc]=pfc; }
    }
    __syncthreads();
    cur ^= 1;
  }
  hst[((size_t)dir*B_ + b0+b1)*HID+u1] = hls[b1][u1];
  cst[((size_t)dir*B_ + b0+b1)*HID+u1] = cr0;
  mst[((size_t)dir*B_ + b0+b1)*HID+u1] = mr0;
  if (has2){
    hst[((size_t)dir*B_ + b0+b2)*HID+u2] = hls[b2][u2];
    cst[((size_t)dir*B_ + b0+b2)*HID+u2] = cr1;
    mst[((size_t)dir*B_ + b0+b2)*HID+u2] = mr1;
  }
  if (last){
    pooled[(size_t)(b0+b1)*300 + dir*HID + u1] = mr0;
    if (has2) pooled[(size_t)(b0+b2)*300 + dir*HID + u2] = mr1;
  }
}

// ---------------- tail: AdaBN2 stats ----------------
__global__ void k_stats2(const float* __restrict__ pooled,
    const float* __restrict__ g2, const float* __restrict__ b2,
    float* __restrict__ a2, float* __restrict__ d2){
  int f = threadIdx.x;
  if (f >= 300) return;
  float s=0.f,q=0.f;
  for (int b=0;b<B_;b++){ float v = pooled[(size_t)b*300+f]; s+=v; q+=v*v; }
  float m = s*(1.f/B_), var = q*(1.f/B_) - m*m;
  float a = g2[f]*rsqrtf(var+EPS);
  a2[f]=a; d2[f]=b2[f]-m*a;
}

// ---------------- fc1 (+folded AdaBN2) + relu ----------------
__global__ void k_fc1(const float* __restrict__ pooled,
    const float* __restrict__ a2, const float* __restrict__ d2,
    const float* __restrict__ w1, const float* __restrict__ fb1,
    float* __restrict__ z1){
  int o = blockIdx.x*256 + threadIdx.x;
  if (o >= B_*50) return;
  int b = o/50, j = o%50;
  float acc = fb1[j];
  for (int f=0;f<300;f++)
    acc += (a2[f]*pooled[(size_t)b*300+f] + d2[f]) * w1[j*300+f];
  z1[o] = fmaxf(acc,0.f);
}

// ---------------- AdaBN3 stats ----------------
__global__ void k_stats3(const float* __restrict__ z1,
    const float* __restrict__ g3, const float* __restrict__ b3,
    float* __restrict__ a3, float* __restrict__ d3){
  int f = threadIdx.x;
  if (f >= 50) return;
  float s=0.f,q=0.f;
  for (int b=0;b<B_;b++){ float v = z1[(size_t)b*50+f]; s+=v; q+=v*v; }
  float m = s*(1.f/B_), var = q*(1.f/B_) - m*m;
  float a = g3[f]*rsqrtf(var+EPS);
  a3[f]=a; d3[f]=b3[f]-m*a;
}

// ---------------- fc2 (+folded AdaBN3) + softmax ----------------
__global__ void k_fc2(const float* __restrict__ z1,
    const float* __restrict__ a3, const float* __restrict__ d3,
    const float* __restrict__ w2, const float* __restrict__ fb2,
    float* __restrict__ out){
  int b = blockIdx.x;
  int t = threadIdx.x;
  __shared__ float zl[50];
  __shared__ float lg[10];
  if (t<50) zl[t] = a3[t]*z1[(size_t)b*50+t] + d3[t];
  __syncthreads();
  if (t<10){
    float acc = fb2[t];
    for (int j=0;j<50;j++) acc += zl[j]*w2[t*50+j];
    lg[t]=acc;
  }
  __syncthreads();
  if (t<10){
    float m = lg[0];
    #pragma unroll
    for (int i=1;i<10;i++) m = fmaxf(m,lg[i]);
    float s = 0.f;
    #pragma unroll
    for (int i=0;i<10;i++) s += expf(lg[i]-m);
    out[(size_t)b*10+t] = expf(lg[t]-m)/s;
  }
}

extern "C" void kernel_launch(void* const* d_in, const int* in_sizes, int n_in,
                              void* d_out, int out_size, void* d_ws, size_t ws_size,
                              hipStream_t stream) {
  const float* x    = (const float*)d_in[0];
  const float* cw   = (const float*)d_in[1];
  const float* cb   = (const float*)d_in[2];
  const float* g1   = (const float*)d_in[3];
  const float* b1v  = (const float*)d_in[4];
  const float* wihf = (const float*)d_in[5];
  const float* whhf = (const float*)d_in[6];
  const float* bihf = (const float*)d_in[7];
  const float* bhhf = (const float*)d_in[8];
  const float* wihb = (const float*)d_in[9];
  const float* whhb = (const float*)d_in[10];
  const float* bihb = (const float*)d_in[11];
  const float* bhhb = (const float*)d_in[12];
  const float* g2   = (const float*)d_in[13];
  const float* b2   = (const float*)d_in[14];
  const float* w1   = (const float*)d_in[15];
  const float* fb1  = (const float*)d_in[16];
  const float* g3   = (const float*)d_in[17];
  const float* b3   = (const float*)d_in[18];
  const float* w2   = (const float*)d_in[19];
  const float* fb2  = (const float*)d_in[20];
  float* out = (float*)d_out;

  uint8_t* base = (uint8_t*)d_ws;
  size_t off = 0;
  auto alloc = [&](size_t nfloats)->float*{
    float* p = (float*)(base + off);
    off = (off + nfloats*4 + 255) & ~(size_t)255;
    return p;
  };
  float* y      = alloc((size_t)B_*LOUT*NF);
  float* st     = alloc(256);
  float* wTf    = alloc((size_t)NF*NPAD);
  float* wTb    = alloc((size_t)NF*NPAD);
  float* bef    = alloc(NPAD);
  float* beb    = alloc(NPAD);
  float* hst    = alloc((size_t)2*B_*HID);
  float* cst    = alloc((size_t)2*B_*HID);
  float* mst    = alloc((size_t)2*B_*HID);
  float* pooled = alloc((size_t)B_*300);
  float* a2     = alloc(320);
  float* d2     = alloc(320);
  float* z1     = alloc((size_t)B_*50);
  float* a3     = alloc(64);
  float* d3     = alloc(64);
  size_t fixedEnd = off;

  // largest tc whose double pre-buffers fit, then equalize chunk sizes
  size_t per_t = (size_t)2*B_*NPAD*4;   // both directions, per timestep
  size_t avail = (ws_size > fixedEnd + 4096) ? (ws_size - fixedEnd - 4096) : 0;
  int tcmax = (int)(avail / per_t);
  if (tcmax < 1) tcmax = 1;
  if (tcmax > LOUT) tcmax = LOUT;
  int nch = (LOUT + tcmax - 1) / tcmax;
  int TC = (LOUT + nch - 1) / nch;
  float* pref = alloc((size_t)TC*B_*NPAD);
  float* preb = alloc((size_t)TC*B_*NPAD);

  hipMemsetAsync(st, 0, 256*4, stream);
  k_conv<<<dim3((LOUT+3)/4, B_), 512, 0, stream>>>(x, cw, cb, y);
  k_stats1<<<1024, 256, 0, stream>>>(y, st);
  k_prep<<<(2*NPAD+255)/256, 256, 0, stream>>>(st, g1, b1v, wihf, wihb,
                                               bihf, bhhf, bihb, bhhb,
                                               wTf, wTb, bef, beb);
  int t0 = 0; int first = 1;
  while (t0 < LOUT){
    int tc = (TC < LOUT - t0) ? TC : (LOUT - t0);
    int lastc = (t0 + tc >= LOUT) ? 1 : 0;
    k_proj<<<dim3(tc*4, 5, 2), 256, 0, stream>>>(y, wTf, wTb, bef, beb,
                                                 pref, preb, t0, tc);
    k_rec<<<256, 512, 0, stream>>>(whhf, whhb, pref, preb, hst, cst, mst,
                                   pooled, tc, first, lastc);
    t0 += tc; first = 0;
  }
  k_stats2<<<1, 320, 0, stream>>>(pooled, g2, b2, a2, d2);
  k_fc1<<<(B_*50+255)/256, 256, 0, stream>>>(pooled, a2, d2, w1, fb1, z1);
  k_stats3<<<1, 64, 0, stream>>>(z1, g3, b3, a3, d3);
  k_fc2<<<B_, 64, 0, stream>>>(z1, a3, d3, w2, fb2, out);
}

// Round 4
// 3481.058 us; speedup vs baseline: 2.2162x; 1.0024x over previous
//
#include <hip/hip_runtime.h>
#include <math.h>

#define B_   512
#define T_   800
#define FIN  3
#define NF   128
#define KW   15
#define HID  150
#define LOUT 393
#define G4   600
#define NPAD 640
#define EPS  1e-5f

__device__ __forceinline__ float hsig(float x){ return fminf(fmaxf(0.2f*x+0.5f,0.f),1.f); }
// NaN-safe fast tanh: exp(+inf)->1, exp(0)->-1
__device__ __forceinline__ float ftanh(float x){ float e=__expf(2.f*x); return 1.f - 2.f/(e+1.f); }

// ---------------- conv + relu + maxpool2 -> y[b][l][c] ----------------
__global__ __launch_bounds__(512) void k_conv(const float* __restrict__ x,
        const float* __restrict__ cw, const float* __restrict__ cb,
        float* __restrict__ y){
  __shared__ float wl[NF*FIN*KW];     // 5760
  __shared__ float xl[FIN][24];
  int tid = threadIdx.x;
  int b = blockIdx.y;
  int l0 = blockIdx.x*4;
  for (int i=tid;i<NF*FIN*KW;i+=512) wl[i]=cw[i];
  if (tid < FIN*22){ int f=tid/22, j=tid%22; int p = 2*l0+j;
     xl[f][j] = (p<T_)? x[(size_t)b*(FIN*T_) + (size_t)f*T_ + p] : 0.f; }
  __syncthreads();
  int c = tid & 127, li = tid >> 7;
  int l = l0 + li;
  if (l >= LOUT) return;
  float wr[FIN*KW];
  #pragma unroll
  for (int i=0;i<FIN*KW;i++) wr[i]=wl[c*FIN*KW+i];
  float xv[FIN][16];
  #pragma unroll
  for (int f=0;f<FIN;f++){
    #pragma unroll
    for (int j=0;j<16;j++) xv[f][j]=xl[f][2*li+j];
  }
  float a0=0.f,a1=0.f;
  #pragma unroll
  for (int f=0;f<FIN;f++){
    #pragma unroll
    for (int k=0;k<KW;k++){ float w=wr[f*KW+k]; a0 += w*xv[f][k]; a1 += w*xv[f][k+1]; }
  }
  float v = fmaxf(fmaxf(a0,a1)+cb[c], 0.f);
  y[((size_t)b*LOUT + l)*NF + c] = v;
}

// ---------------- per-channel stats over (b,l), vectorized ----------------
__global__ __launch_bounds__(256) void k_stats1(const float* __restrict__ y, float* __restrict__ st){
  __shared__ float ls[8][256];
  int tid = threadIdx.x;
  int row = tid >> 5, cg = tid & 31;
  for (int i=tid;i<8*256;i+=256) (&ls[0][0])[i]=0.f;
  __syncthreads();
  size_t N4 = (size_t)B_*LOUT*32;     // float4 count (128 ch = 32 float4)
  const float4* y4 = (const float4*)y;
  float s[4]={0,0,0,0}, q[4]={0,0,0,0};
  for (size_t i=(size_t)blockIdx.x*256+tid; i<N4; i+=(size_t)1024*256){
    float4 v=y4[i];
    s[0]+=v.x; q[0]+=v.x*v.x; s[1]+=v.y; q[1]+=v.y*v.y;
    s[2]+=v.z; q[2]+=v.z*v.z; s[3]+=v.w; q[3]+=v.w*v.w;
  }
  #pragma unroll
  for (int j=0;j<4;j++){ ls[row][cg*4+j]+=s[j]; ls[row][128+cg*4+j]+=q[j]; }
  __syncthreads();
  float tot=0.f;
  #pragma unroll
  for (int r=0;r<8;r++) tot += ls[r][tid];
  atomicAdd(&st[tid], tot);
}

// -------- fold AdaBN1 into projection weights: wT[f][n], bias_eff[n] --------
__global__ void k_prep(const float* __restrict__ st,
    const float* __restrict__ g1, const float* __restrict__ b1v,
    const float* __restrict__ wf, const float* __restrict__ wb,
    const float* __restrict__ bif, const float* __restrict__ bhf,
    const float* __restrict__ bib, const float* __restrict__ bhb,
    float* __restrict__ wTf, float* __restrict__ wTb,
    float* __restrict__ bef, float* __restrict__ beb){
  int id = blockIdx.x*256 + threadIdx.x;
  if (id >= 2*NPAD) return;
  int dir = id/NPAD, g = id%NPAD;
  float* wT = dir? wTb : wTf;
  float* be = dir? beb : bef;
  if (g >= G4){ for (int f=0;f<NF;f++) wT[(size_t)f*NPAD+g]=0.f; be[g]=0.f; return; }
  const float* wih = dir? wb : wf;
  float bias = dir? (bib[g]+bhb[g]) : (bif[g]+bhf[g]);
  const float Ninv = 1.f/((float)B_*(float)LOUT);
  for (int f=0;f<NF;f++){
    float m = st[f]*Ninv;
    float var = st[NF+f]*Ninv - m*m;
    float a = g1[f]*rsqrtf(var+EPS);
    float d = b1v[f] - m*a;
    float w = wih[g*NF+f];
    wT[(size_t)f*NPAD+g] = a*w;
    bias += d*w;
  }
  be[g] = bias;
}

// ---------------- projection GEMM: pre[trel*512+b][n] = y[b][t].wT + be ----------------
// 128x128 tile, 256 threads, 8x8 acc, K tiled by 64 (66KB LDS -> 2 blocks/CU)
__global__ __launch_bounds__(256, 2) void k_proj(const float* __restrict__ y,
    const float* __restrict__ wTf, const float* __restrict__ wTb,
    const float* __restrict__ bef, const float* __restrict__ beb,
    float* __restrict__ pref, float* __restrict__ preb,
    int t0f, int tc){
  __shared__ float As[64*132];   // k-major: As[k*132 + m]
  __shared__ float Bs[64*132];   // Bs[k*132 + n]
  int dir = blockIdx.z;
  const float* wT = dir? wTb : wTf;
  const float* be = dir? beb : bef;
  float* pre = dir? preb : pref;
  int tid = threadIdx.x;
  int m0 = blockIdx.x*128, n0 = blockIdx.y*128;
  int trel = m0>>9, bb = m0&511;
  int t = dir ? (LOUT-1-t0f-trel) : (t0f+trel);
  int lane = tid & 63, wv = tid>>6;
  int mi = ((lane&3) + wv*4)*8;   // A-read: 4 addrs/wave, 16-lane broadcast
  int ni = (lane>>2)*8;
  int ar = tid>>1, ah = tid&1;    // A stage: row, which 32-k half
  int bk = tid>>5, bn = (tid&31)*4; // B stage: k row base, n col (float4)
  float acc[8][8];
  #pragma unroll
  for (int i=0;i<8;i++)
    #pragma unroll
    for (int j=0;j<8;j++) acc[i][j]=0.f;

  const float* arow = y + ((size_t)(bb+ar)*LOUT + t)*NF + ah*32;
  #pragma unroll
  for (int kt=0; kt<2; kt++){
    if (kt) __syncthreads();
    #pragma unroll
    for (int q=0;q<8;q++){
      float4 v = *(const float4*)(arow + kt*64 + q*4);
      int kk = ah*32 + q*4;
      As[(kk+0)*132+ar]=v.x; As[(kk+1)*132+ar]=v.y; As[(kk+2)*132+ar]=v.z; As[(kk+3)*132+ar]=v.w;
    }
    #pragma unroll
    for (int j=0;j<8;j++){
      int kk = bk + j*8;
      *(float4*)&Bs[kk*132 + bn] = *(const float4*)&wT[(size_t)(kt*64+kk)*NPAD + n0 + bn];
    }
    __syncthreads();
    #pragma unroll 4
    for (int k=0;k<64;k++){
      float4 a0=*(const float4*)&As[k*132+mi], a1=*(const float4*)&As[k*132+mi+4];
      float4 b0=*(const float4*)&Bs[k*132+ni], b1=*(const float4*)&Bs[k*132+ni+4];
      float av[8]={a0.x,a0.y,a0.z,a0.w,a1.x,a1.y,a1.z,a1.w};
      float bv[8]={b0.x,b0.y,b0.z,b0.w,b1.x,b1.y,b1.z,b1.w};
      #pragma unroll
      for (int i=0;i<8;i++)
        #pragma unroll
        for (int j=0;j<8;j++) acc[i][j] += av[i]*bv[j];
    }
  }
  float4 bl0=*(const float4*)&be[n0+ni], bl1=*(const float4*)&be[n0+ni+4];
  float bv[8]={bl0.x,bl0.y,bl0.z,bl0.w,bl1.x,bl1.y,bl1.z,bl1.w};
  #pragma unroll
  for (int i=0;i<8;i++){
    float* dst = pre + (size_t)(m0+mi+i)*NPAD + n0 + ni;
    float4 o0={acc[i][0]+bv[0],acc[i][1]+bv[1],acc[i][2]+bv[2],acc[i][3]+bv[3]};
    float4 o1={acc[i][4]+bv[4],acc[i][5]+bv[5],acc[i][6]+bv[6],acc[i][7]+bv[7]};
    *(float4*)dst = o0; *(float4*)(dst+4) = o1;
  }
}

// ---------------- recurrence: register-resident w_hh, fused time-max ----------------
// waves_per_eu(2,2): cap occupancy at 2 waves/EU (= this kernel's own 8-wave block,
// 1 block/CU) so the allocator may use 256 VGPRs and keep w[5][38]=190 in registers.
__global__ __launch_bounds__(512)
__attribute__((amdgpu_waves_per_eu(2, 2)))
void k_rec(const float* __restrict__ whf,
    const float* __restrict__ whb,
    const float* __restrict__ pref, const float* __restrict__ preb,
    float* __restrict__ hst, float* __restrict__ cst, float* __restrict__ mst,
    float* __restrict__ pooled, int tc, int first, int last){
  int dir = blockIdx.x >> 7;
  int b0 = (blockIdx.x & 127)*4;
  const float* wh  = dir? whb : whf;
  const float* pre = dir? preb : pref;
  int tid = threadIdx.x;
  int lane = tid & 63, wv = tid >> 6;
  int gl = lane & 15, kl = lane >> 4;
  int glc = (gl<15)? gl : 14;          // clamp lane 15 -> duplicate work, writes masked
  int gbase = wv*75 + glc*5;
  int kq = kl*38;                       // 4x38 = 152 covers 150 (+2 zero pad)

  __shared__ float hls[4][160];         // h state, zero-padded 150..159
  __shared__ float dls[4][608];         // gate matvec results
  __shared__ float pls[2][4][608];      // pre double buffer

  // weights -> registers, direct global loads (L2/L3-broadcast across blocks)
  float w[5][38];
  #pragma unroll
  for (int i=0;i<5;i++){
    const float* wrow = wh + (size_t)(gbase+i)*HID + kq;
    #pragma unroll
    for (int j=0;j<38;j++) w[i][j] = (kq+j < HID)? wrow[j] : 0.f;
  }

  int u1 = tid % 150, b1 = tid / 150;
  int u2 = (tid+512) % 150, b2 = (tid+512) / 150;
  bool has2 = tid < 88;
  float cr0, cr1=0.f, mr0, mr1=-1e30f;
  if (first){
    cr0=0.f; mr0=-1e30f;
    for (int i=tid;i<4*160;i+=512) (&hls[0][0])[i]=0.f;
  } else {
    cr0 = cst[((size_t)dir*B_ + b0+b1)*HID + u1];
    mr0 = mst[((size_t)dir*B_ + b0+b1)*HID + u1];
    if (has2){
      cr1 = cst[((size_t)dir*B_ + b0+b2)*HID + u2];
      mr1 = mst[((size_t)dir*B_ + b0+b2)*HID + u2];
    }
    for (int i=tid;i<4*160;i+=512){ int bq=i/160, uu=i%160;
      (&hls[0][0])[i] = (uu<HID)? hst[((size_t)dir*B_ + b0+bq)*HID+uu] : 0.f; }
  }
  // preload pre[t=0] (4 rows x 608 floats = 1216 float2)
  for (int j=tid;j<1216;j+=512){ int r=j/304, cc=j%304;
    ((float2*)&pls[0][r][0])[cc] =
      ((const float2*)(pre + (size_t)(b0+r)*NPAD))[cc];
  }
  __syncthreads();

  int cur=0;
  for (int t=0;t<tc;t++){
    // prefetch next pre -> regs
    float2 pfa, pfb, pfc;
    bool ld = (t+1 < tc), l3 = tid < 192;
    if (ld){
      size_t base = (size_t)(t+1)*B_ + b0;
      { int j=tid;      int r=j/304, cc=j%304; pfa = ((const float2*)(pre + (base+r)*NPAD))[cc]; }
      { int j=tid+512;  int r=j/304, cc=j%304; pfb = ((const float2*)(pre + (base+r)*NPAD))[cc]; }
      if (l3){ int j=tid+1024; int r=j/304, cc=j%304; pfc = ((const float2*)(pre + (base+r)*NPAD))[cc]; }
    }
    // matvec: batches 0,1
    {
      const float2* h0 = (const float2*)&hls[0][kq];
      const float2* h1 = (const float2*)&hls[1][kq];
      float acc[5][2];
      #pragma unroll
      for (int i=0;i<5;i++){acc[i][0]=0.f;acc[i][1]=0.f;}
      #pragma unroll
      for (int p=0;p<19;p++){
        float2 ha=h0[p], hb=h1[p];
        #pragma unroll
        for (int i=0;i<5;i++){
          acc[i][0] += w[i][2*p]*ha.x + w[i][2*p+1]*ha.y;
          acc[i][1] += w[i][2*p]*hb.x + w[i][2*p+1]*hb.y;
        }
      }
      #pragma unroll
      for (int i=0;i<5;i++){
        acc[i][0] += __shfl_xor(acc[i][0],16); acc[i][0] += __shfl_xor(acc[i][0],32);
        acc[i][1] += __shfl_xor(acc[i][1],16); acc[i][1] += __shfl_xor(acc[i][1],32);
      }
      if (kl==0 && gl<15){
        #pragma unroll
        for (int i=0;i<5;i++){ dls[0][gbase+i]=acc[i][0]; dls[1][gbase+i]=acc[i][1]; }
      }
    }
    // matvec: batches 2,3
    {
      const float2* h2 = (const float2*)&hls[2][kq];
      const float2* h3 = (const float2*)&hls[3][kq];
      float acc[5][2];
      #pragma unroll
      for (int i=0;i<5;i++){acc[i][0]=0.f;acc[i][1]=0.f;}
      #pragma unroll
      for (int p=0;p<19;p++){
        float2 ha=h2[p], hb=h3[p];
        #pragma unroll
        for (int i=0;i<5;i++){
          acc[i][0] += w[i][2*p]*ha.x + w[i][2*p+1]*ha.y;
          acc[i][1] += w[i][2*p]*hb.x + w[i][2*p+1]*hb.y;
        }
      }
      #pragma unroll
      for (int i=0;i<5;i++){
        acc[i][0] += __shfl_xor(acc[i][0],16); acc[i][0] += __shfl_xor(acc[i][0],32);
        acc[i][1] += __shfl_xor(acc[i][1],16); acc[i][1] += __shfl_xor(acc[i][1],32);
      }
      if (kl==0 && gl<15){
        #pragma unroll
        for (int i=0;i<5;i++){ dls[2][gbase+i]=acc[i][0]; dls[3][gbase+i]=acc[i][1]; }
      }
    }
    __syncthreads();
    // gates, cell update, running max  (unit (b1,u1) per thread, +88 extras)
    {
      float pi = dls[b1][u1]      + pls[cur][b1][u1];
      float pf = dls[b1][150+u1]  + pls[cur][b1][150+u1];
      float pg = dls[b1][300+u1]  + pls[cur][b1][300+u1];
      float po = dls[b1][450+u1]  + pls[cur][b1][450+u1];
      float ig=hsig(pi), fg=hsig(pf), og=hsig(po), gg=ftanh(pg);
      cr0 = fg*cr0 + ig*gg;
      float hv = og*ftanh(cr0);
      mr0 = fmaxf(mr0,hv);
      hls[b1][u1] = hv;
      if (has2){
        float pi2 = dls[b2][u2]      + pls[cur][b2][u2];
        float pf2 = dls[b2][150+u2]  + pls[cur][b2][150+u2];
        float pg2 = dls[b2][300+u2]  + pls[cur][b2][300+u2];
        float po2 = dls[b2][450+u2]  + pls[cur][b2][450+u2];
        float ig2=hsig(pi2), fg2=hsig(pf2), og2=hsig(po2), gg2=ftanh(pg2);
        cr1 = fg2*cr1 + ig2*gg2;
        float hv2 = og2*ftanh(cr1);
        mr1 = fmaxf(mr1,hv2);
        hls[b2][u2] = hv2;
      }
    }
    if (ld){
      int nx = cur^1;
      { int j=tid;      int r=j/304, cc=j%304; ((float2*)&pls[nx][r][0])[cc]=pfa; }
      { int j=tid+512;  int r=j/304, cc=j%304; ((float2*)&pls[nx][r][0])[cc]=pfb; }
      if (l3){ int j=tid+1024; int r=j/304, cc=j%304; ((float2*)&pls[nx][r][0])[cc]=pfc; }
    }
    __syncthreads();
    cur ^= 1;
  }
  hst[((size_t)dir*B_ + b0+b1)*HID+u1] = hls[b1][u1];
  cst[((size_t)dir*B_ + b0+b1)*HID+u1] = cr0;
  mst[((size_t)dir*B_ + b0+b1)*HID+u1] = mr0;
  if (has2){
    hst[((size_t)dir*B_ + b0+b2)*HID+u2] = hls[b2][u2];
    cst[((size_t)dir*B_ + b0+b2)*HID+u2] = cr1;
    mst[((size_t)dir*B_ + b0+b2)*HID+u2] = mr1;
  }
  if (last){
    pooled[(size_t)(b0+b1)*300 + dir*HID + u1] = mr0;
    if (has2) pooled[(size_t)(b0+b2)*300 + dir*HID + u2] = mr1;
  }
}

// ---------------- tail: AdaBN2 stats ----------------
__global__ void k_stats2(const float* __restrict__ pooled,
    const float* __restrict__ g2, const float* __restrict__ b2,
    float* __restrict__ a2, float* __restrict__ d2){
  int f = threadIdx.x;
  if (f >= 300) return;
  float s=0.f,q=0.f;
  for (int b=0;b<B_;b++){ float v = pooled[(size_t)b*300+f]; s+=v; q+=v*v; }
  float m = s*(1.f/B_), var = q*(1.f/B_) - m*m;
  float a = g2[f]*rsqrtf(var+EPS);
  a2[f]=a; d2[f]=b2[f]-m*a;
}

// ---------------- fc1 (+folded AdaBN2) + relu ----------------
__global__ void k_fc1(const float* __restrict__ pooled,
    const float* __restrict__ a2, const float* __restrict__ d2,
    const float* __restrict__ w1, const float* __restrict__ fb1,
    float* __restrict__ z1){
  int o = blockIdx.x*256 + threadIdx.x;
  if (o >= B_*50) return;
  int b = o/50, j = o%50;
  float acc = fb1[j];
  for (int f=0;f<300;f++)
    acc += (a2[f]*pooled[(size_t)b*300+f] + d2[f]) * w1[j*300+f];
  z1[o] = fmaxf(acc,0.f);
}

// ---------------- AdaBN3 stats ----------------
__global__ void k_stats3(const float* __restrict__ z1,
    const float* __restrict__ g3, const float* __restrict__ b3,
    float* __restrict__ a3, float* __restrict__ d3){
  int f = threadIdx.x;
  if (f >= 50) return;
  float s=0.f,q=0.f;
  for (int b=0;b<B_;b++){ float v = z1[(size_t)b*50+f]; s+=v; q+=v*v; }
  float m = s*(1.f/B_), var = q*(1.f/B_) - m*m;
  float a = g3[f]*rsqrtf(var+EPS);
  a3[f]=a; d3[f]=b3[f]-m*a;
}

// ---------------- fc2 (+folded AdaBN3) + softmax ----------------
__global__ void k_fc2(const float* __restrict__ z1,
    const float* __restrict__ a3, const float* __restrict__ d3,
    const float* __restrict__ w2, const float* __restrict__ fb2,
    float* __restrict__ out){
  int b = blockIdx.x;
  int t = threadIdx.x;
  __shared__ float zl[50];
  __shared__ float lg[10];
  if (t<50) zl[t] = a3[t]*z1[(size_t)b*50+t] + d3[t];
  __syncthreads();
  if (t<10){
    float acc = fb2[t];
    for (int j=0;j<50;j++) acc += zl[j]*w2[t*50+j];
    lg[t]=acc;
  }
  __syncthreads();
  if (t<10){
    float m = lg[0];
    #pragma unroll
    for (int i=1;i<10;i++) m = fmaxf(m,lg[i]);
    float s = 0.f;
    #pragma unroll
    for (int i=0;i<10;i++) s += expf(lg[i]-m);
    out[(size_t)b*10+t] = expf(lg[t]-m)/s;
  }
}

extern "C" void kernel_launch(void* const* d_in, const int* in_sizes, int n_in,
                              void* d_out, int out_size, void* d_ws, size_t ws_size,
                              hipStream_t stream) {
  const float* x    = (const float*)d_in[0];
  const float* cw   = (const float*)d_in[1];
  const float* cb   = (const float*)d_in[2];
  const float* g1   = (const float*)d_in[3];
  const float* b1v  = (const float*)d_in[4];
  const float* wihf = (const float*)d_in[5];
  const float* whhf = (const float*)d_in[6];
  const float* bihf = (const float*)d_in[7];
  const float* bhhf = (const float*)d_in[8];
  const float* wihb = (const float*)d_in[9];
  const float* whhb = (const float*)d_in[10];
  const float* bihb = (const float*)d_in[11];
  const float* bhhb = (const float*)d_in[12];
  const float* g2   = (const float*)d_in[13];
  const float* b2   = (const float*)d_in[14];
  const float* w1   = (const float*)d_in[15];
  const float* fb1  = (const float*)d_in[16];
  const float* g3   = (const float*)d_in[17];
  const float* b3   = (const float*)d_in[18];
  const float* w2   = (const float*)d_in[19];
  const float* fb2  = (const float*)d_in[20];
  float* out = (float*)d_out;

  uint8_t* base = (uint8_t*)d_ws;
  size_t off = 0;
  auto alloc = [&](size_t nfloats)->float*{
    float* p = (float*)(base + off);
    off = (off + nfloats*4 + 255) & ~(size_t)255;
    return p;
  };
  float* y      = alloc((size_t)B_*LOUT*NF);
  float* st     = alloc(256);
  float* wTf    = alloc((size_t)NF*NPAD);
  float* wTb    = alloc((size_t)NF*NPAD);
  float* bef    = alloc(NPAD);
  float* beb    = alloc(NPAD);
  float* hst    = alloc((size_t)2*B_*HID);
  float* cst    = alloc((size_t)2*B_*HID);
  float* mst    = alloc((size_t)2*B_*HID);
  float* pooled = alloc((size_t)B_*300);
  float* a2     = alloc(320);
  float* d2     = alloc(320);
  float* z1     = alloc((size_t)B_*50);
  float* a3     = alloc(64);
  float* d3     = alloc(64);
  size_t fixedEnd = off;

  // largest tc whose double pre-buffers fit, then equalize chunk sizes
  size_t per_t = (size_t)2*B_*NPAD*4;   // both directions, per timestep
  size_t avail = (ws_size > fixedEnd + 4096) ? (ws_size - fixedEnd - 4096) : 0;
  int tcmax = (int)(avail / per_t);
  if (tcmax < 1) tcmax = 1;
  if (tcmax > LOUT) tcmax = LOUT;
  int nch = (LOUT + tcmax - 1) / tcmax;
  int TC = (LOUT + nch - 1) / nch;
  float* pref = alloc((size_t)TC*B_*NPAD);
  float* preb = alloc((size_t)TC*B_*NPAD);

  hipMemsetAsync(st, 0, 256*4, stream);
  k_conv<<<dim3((LOUT+3)/4, B_), 512, 0, stream>>>(x, cw, cb, y);
  k_stats1<<<1024, 256, 0, stream>>>(y, st);
  k_prep<<<(2*NPAD+255)/256, 256, 0, stream>>>(st, g1, b1v, wihf, wihb,
                                               bihf, bhhf, bihb, bhhb,
                                               wTf, wTb, bef, beb);
  int t0 = 0; int first = 1;
  while (t0 < LOUT){
    int tc = (TC < LOUT - t0) ? TC : (LOUT - t0);
    int lastc = (t0 + tc >= LOUT) ? 1 : 0;
    k_proj<<<dim3(tc*4, 5, 2), 256, 0, stream>>>(y, wTf, wTb, bef, beb,
                                                 pref, preb, t0, tc);
    k_rec<<<256, 512, 0, stream>>>(whhf, whhb, pref, preb, hst, cst, mst,
                                   pooled, tc, first, lastc);
    t0 += tc; first = 0;
  }
  k_stats2<<<1, 320, 0, stream>>>(pooled, g2, b2, a2, d2);
  k_fc1<<<(B_*50+255)/256, 256, 0, stream>>>(pooled, a2, d2, w1, fb1, z1);
  k_stats3<<<1, 64, 0, stream>>>(z1, g3, b3, a3, d3);
  k_fc2<<<B_, 64, 0, stream>>>(z1, a3, d3, w2, fb2, out);
}

// Round 5
// 1917.519 us; speedup vs baseline: 4.0233x; 1.8154x over previous
//
#include <hip/hip_runtime.h>
#include <math.h>

#define B_   512
#define T_   800
#define FIN  3
#define NF   128
#define KW   15
#define HID  150
#define LOUT 393
#define G4   600
#define NPAD 640
#define EPS  1e-5f

#define NT_  38          // N tiles of 16 over 608 (600 gates + pad)
#define KT_  5           // K tiles of 32 over 160 (150 + pad)
#define HSTR 152         // per-(dir,batch) state stride

typedef _Float16 half8 __attribute__((ext_vector_type(8)));
typedef float f32x4 __attribute__((ext_vector_type(4)));

__device__ __forceinline__ float hsig(float x){ return fminf(fmaxf(0.2f*x+0.5f,0.f),1.f); }
// NaN-safe fast tanh
__device__ __forceinline__ float ftanh(float x){ float e=__expf(2.f*x); return 1.f - 2.f/(e+1.f); }

// ---------------- conv + relu + maxpool2 -> y[b][l][c] ----------------
__global__ __launch_bounds__(512) void k_conv(const float* __restrict__ x,
        const float* __restrict__ cw, const float* __restrict__ cb,
        float* __restrict__ y){
  __shared__ float wl[NF*FIN*KW];
  __shared__ float xl[FIN][24];
  int tid = threadIdx.x;
  int b = blockIdx.y;
  int l0 = blockIdx.x*4;
  for (int i=tid;i<NF*FIN*KW;i+=512) wl[i]=cw[i];
  if (tid < FIN*22){ int f=tid/22, j=tid%22; int p = 2*l0+j;
     xl[f][j] = (p<T_)? x[(size_t)b*(FIN*T_) + (size_t)f*T_ + p] : 0.f; }
  __syncthreads();
  int c = tid & 127, li = tid >> 7;
  int l = l0 + li;
  if (l >= LOUT) return;
  float wr[FIN*KW];
  #pragma unroll
  for (int i=0;i<FIN*KW;i++) wr[i]=wl[c*FIN*KW+i];
  float xv[FIN][16];
  #pragma unroll
  for (int f=0;f<FIN;f++){
    #pragma unroll
    for (int j=0;j<16;j++) xv[f][j]=xl[f][2*li+j];
  }
  float a0=0.f,a1=0.f;
  #pragma unroll
  for (int f=0;f<FIN;f++){
    #pragma unroll
    for (int k=0;k<KW;k++){ float w=wr[f*KW+k]; a0 += w*xv[f][k]; a1 += w*xv[f][k+1]; }
  }
  float v = fmaxf(fmaxf(a0,a1)+cb[c], 0.f);
  y[((size_t)b*LOUT + l)*NF + c] = v;
}

// ---------------- per-channel stats over (b,l), vectorized ----------------
__global__ __launch_bounds__(256) void k_stats1(const float* __restrict__ y, float* __restrict__ st){
  __shared__ float ls[8][256];
  int tid = threadIdx.x;
  int row = tid >> 5, cg = tid & 31;
  for (int i=tid;i<8*256;i+=256) (&ls[0][0])[i]=0.f;
  __syncthreads();
  size_t N4 = (size_t)B_*LOUT*32;
  const float4* y4 = (const float4*)y;
  float s[4]={0,0,0,0}, q[4]={0,0,0,0};
  for (size_t i=(size_t)blockIdx.x*256+tid; i<N4; i+=(size_t)1024*256){
    float4 v=y4[i];
    s[0]+=v.x; q[0]+=v.x*v.x; s[1]+=v.y; q[1]+=v.y*v.y;
    s[2]+=v.z; q[2]+=v.z*v.z; s[3]+=v.w; q[3]+=v.w*v.w;
  }
  #pragma unroll
  for (int j=0;j<4;j++){ ls[row][cg*4+j]+=s[j]; ls[row][128+cg*4+j]+=q[j]; }
  __syncthreads();
  float tot=0.f;
  #pragma unroll
  for (int r=0;r<8;r++) tot += ls[r][tid];
  atomicAdd(&st[tid], tot);
}

// -------- fold AdaBN1 into projection weights: wT[f][n], bias_eff[n] --------
__global__ void k_prep(const float* __restrict__ st,
    const float* __restrict__ g1, const float* __restrict__ b1v,
    const float* __restrict__ wf, const float* __restrict__ wb,
    const float* __restrict__ bif, const float* __restrict__ bhf,
    const float* __restrict__ bib, const float* __restrict__ bhb,
    float* __restrict__ wTf, float* __restrict__ wTb,
    float* __restrict__ bef, float* __restrict__ beb){
  int id = blockIdx.x*256 + threadIdx.x;
  if (id >= 2*NPAD) return;
  int dir = id/NPAD, g = id%NPAD;
  float* wT = dir? wTb : wTf;
  float* be = dir? beb : bef;
  if (g >= G4){ for (int f=0;f<NF;f++) wT[(size_t)f*NPAD+g]=0.f; be[g]=0.f; return; }
  const float* wih = dir? wb : wf;
  float bias = dir? (bib[g]+bhb[g]) : (bif[g]+bhf[g]);
  const float Ninv = 1.f/((float)B_*(float)LOUT);
  for (int f=0;f<NF;f++){
    float m = st[f]*Ninv;
    float var = st[NF+f]*Ninv - m*m;
    float a = g1[f]*rsqrtf(var+EPS);
    float d = b1v[f] - m*a;
    float w = wih[g*NF+f];
    wT[(size_t)f*NPAD+g] = a*w;
    bias += d*w;
  }
  be[g] = bias;
}

// -------- pack w_hh into f16 MFMA B-fragments: wfrag[dir][nt][kt][lane][8] --------
// B[k][n] = w_hh[n][k]; lane l elem j -> k = kt*32 + (l>>4)*8 + j, n = nt*16 + (l&15)
__global__ void k_prep_whh(const float* __restrict__ whf, const float* __restrict__ whb,
                           _Float16* __restrict__ wfrag){
  int id = blockIdx.x*256 + threadIdx.x;
  if (id >= 2*NT_*KT_*64) return;
  int lane = id & 63;
  int rest = id >> 6;             // dir*NT_*KT_ + nt*KT_ + kt
  int kt = rest % KT_;
  int nt = (rest/KT_) % NT_;
  int dir = rest / (KT_*NT_);
  const float* wh = dir? whb : whf;
  int n = nt*16 + (lane&15);
  int kb = kt*32 + (lane>>4)*8;
  half8 v;
  #pragma unroll
  for (int j=0;j<8;j++){
    int k = kb + j;
    float f = (n < G4 && k < HID) ? wh[(size_t)n*HID + k] : 0.f;
    v[j] = (_Float16)f;
  }
  *(half8*)&wfrag[(size_t)id*8] = v;
}

// ---------------- projection GEMM (fp32, unchanged) ----------------
__global__ __launch_bounds__(256, 2) void k_proj(const float* __restrict__ y,
    const float* __restrict__ wTf, const float* __restrict__ wTb,
    const float* __restrict__ bef, const float* __restrict__ beb,
    float* __restrict__ pref, float* __restrict__ preb,
    int t0f, int tc){
  __shared__ float As[64*132];
  __shared__ float Bs[64*132];
  int dir = blockIdx.z;
  const float* wT = dir? wTb : wTf;
  const float* be = dir? beb : bef;
  float* pre = dir? preb : pref;
  int tid = threadIdx.x;
  int m0 = blockIdx.x*128, n0 = blockIdx.y*128;
  int trel = m0>>9, bb = m0&511;
  int t = dir ? (LOUT-1-t0f-trel) : (t0f+trel);
  int lane = tid & 63, wv = tid>>6;
  int mi = ((lane&3) + wv*4)*8;
  int ni = (lane>>2)*8;
  int ar = tid>>1, ah = tid&1;
  int bk = tid>>5, bn = (tid&31)*4;
  float acc[8][8];
  #pragma unroll
  for (int i=0;i<8;i++)
    #pragma unroll
    for (int j=0;j<8;j++) acc[i][j]=0.f;

  const float* arow = y + ((size_t)(bb+ar)*LOUT + t)*NF + ah*32;
  #pragma unroll
  for (int kt=0; kt<2; kt++){
    if (kt) __syncthreads();
    #pragma unroll
    for (int q=0;q<8;q++){
      float4 v = *(const float4*)(arow + kt*64 + q*4);
      int kk = ah*32 + q*4;
      As[(kk+0)*132+ar]=v.x; As[(kk+1)*132+ar]=v.y; As[(kk+2)*132+ar]=v.z; As[(kk+3)*132+ar]=v.w;
    }
    #pragma unroll
    for (int j=0;j<8;j++){
      int kk = bk + j*8;
      *(float4*)&Bs[kk*132 + bn] = *(const float4*)&wT[(size_t)(kt*64+kk)*NPAD + n0 + bn];
    }
    __syncthreads();
    #pragma unroll 4
    for (int k=0;k<64;k++){
      float4 a0=*(const float4*)&As[k*132+mi], a1=*(const float4*)&As[k*132+mi+4];
      float4 b0=*(const float4*)&Bs[k*132+ni], b1=*(const float4*)&Bs[k*132+ni+4];
      float av[8]={a0.x,a0.y,a0.z,a0.w,a1.x,a1.y,a1.z,a1.w};
      float bv[8]={b0.x,b0.y,b0.z,b0.w,b1.x,b1.y,b1.z,b1.w};
      #pragma unroll
      for (int i=0;i<8;i++)
        #pragma unroll
        for (int j=0;j<8;j++) acc[i][j] += av[i]*bv[j];
    }
  }
  float4 bl0=*(const float4*)&be[n0+ni], bl1=*(const float4*)&be[n0+ni+4];
  float bv[8]={bl0.x,bl0.y,bl0.z,bl0.w,bl1.x,bl1.y,bl1.z,bl1.w};
  #pragma unroll
  for (int i=0;i<8;i++){
    float* dst = pre + (size_t)(m0+mi+i)*NPAD + n0 + ni;
    float4 o0={acc[i][0]+bv[0],acc[i][1]+bv[1],acc[i][2]+bv[2],acc[i][3]+bv[3]};
    float4 o1={acc[i][4]+bv[4],acc[i][5]+bv[5],acc[i][6]+bv[6],acc[i][7]+bv[7]};
    *(float4*)dst = o0; *(float4*)(dst+4) = o1;
  }
}

// ---------------- recurrence via f16 MFMA ----------------
// Block: 16 batches x 1 dir, 1024 threads (16 waves). Per step:
//   pre_hh(16x608) = h(16x160,f16) @ w_hh^T via 38 Ntiles x 5 Ktiles mfma_f32_16x16x32_f16
//   gates+cell in fp32; h -> f16 LDS; pre_x prefetched from global one step ahead.
__global__ __launch_bounds__(1024)
__attribute__((amdgpu_waves_per_eu(4, 4)))
void k_rec2(const _Float16* __restrict__ wfrag,
            const float* __restrict__ pref, const float* __restrict__ preb,
            float* __restrict__ hst, float* __restrict__ cst, float* __restrict__ mst,
            float* __restrict__ pooled, int tc, int first, int last){
  int dir = blockIdx.x >> 5;
  int b0 = (blockIdx.x & 31) * 16;
  const float* pre = dir? preb : pref;
  int tid = threadIdx.x;
  int lane = tid & 63, w = tid >> 6;

  __shared__ __align__(16) _Float16 hh[16][168];   // h state f16, zero-padded
  __shared__ float dls[16][612];                   // pre_hh results

  // ---- load B fragments (weights) into registers ----
  int cnt  = (w<6) ? 3 : 2;
  int base = (w<6) ? 3*w : 18 + 2*(w-6);
  const _Float16* wf = wfrag + (size_t)dir*NT_*KT_*64*8;
  half8 bfr[3][5];
  #pragma unroll
  for (int i=0;i<3;i++){
    #pragma unroll
    for (int kt=0;kt<KT_;kt++){
      int ntc = (i<cnt)? (base+i) : base;   // clamp (unused tiles load tile 'base')
      bfr[i][kt] = *(const half8*)&wf[(size_t)((ntc*KT_+kt)*64 + lane)*8];
    }
  }

  // ---- cell-unit mapping: 3 ids per thread over 16x152 ----
  int bl[3], uu[3], blc[3];
  bool valid[3];
  #pragma unroll
  for (int k=0;k<3;k++){
    int id = tid + k*1024;
    int b = id / HSTR, u = id - b*HSTR;
    bl[k]=b; uu[k]=u; blc[k]=b & 15;
    valid[k] = (id < 16*HSTR) && (u < HID);
  }

  // ---- init h/c/m state ----
  for (int i=tid; i<16*168; i+=1024) (&hh[0][0])[i] = (_Float16)0.f;
  __syncthreads();
  float c[3], m[3], hlast[3];
  #pragma unroll
  for (int k=0;k<3;k++){ c[k]=0.f; m[k]=-1e30f; hlast[k]=0.f; }
  if (!first){
    #pragma unroll
    for (int k=0;k<3;k++){
      if (valid[k]){
        size_t gi = ((size_t)(dir*B_ + b0 + bl[k]))*HSTR + uu[k];
        c[k]=cst[gi]; m[k]=mst[gi];
        float hv = hst[gi]; hlast[k]=hv;
        hh[bl[k]][uu[k]] = (_Float16)hv;
      }
    }
  }
  // prefetch pre[t=0]
  float pf[12];
  #pragma unroll
  for (int k=0;k<3;k++){
    const float* pr = pre + ((size_t)(b0 + blc[k]))*NPAD + uu[k];
    #pragma unroll
    for (int g=0;g<4;g++) pf[k*4+g] = pr[g*HID];
  }
  __syncthreads();

  int arow = lane & 15;
  int koff = (lane>>4)*8;
  int drow = (lane>>4)*4;

  for (int t=0; t<tc; t++){
    // issue prefetch for t+1 (latency hides under MFMA + sync)
    float pn[12];
    #pragma unroll
    for (int j=0;j<12;j++) pn[j]=0.f;
    if (t+1 < tc){
      #pragma unroll
      for (int k=0;k<3;k++){
        const float* pr = pre + ((size_t)(t+1)*B_ + b0 + blc[k])*NPAD + uu[k];
        #pragma unroll
        for (int g=0;g<4;g++) pn[k*4+g] = pr[g*HID];
      }
    }
    // ---- MFMA phase ----
    f32x4 acc0={0,0,0,0}, acc1={0,0,0,0}, acc2={0,0,0,0};
    #pragma unroll
    for (int kt=0; kt<KT_; kt++){
      half8 a = *(const half8*)&hh[arow][kt*32 + koff];
      acc0 = __builtin_amdgcn_mfma_f32_16x16x32_f16(a, bfr[0][kt], acc0, 0,0,0);
      acc1 = __builtin_amdgcn_mfma_f32_16x16x32_f16(a, bfr[1][kt], acc1, 0,0,0);
      if (cnt>2) acc2 = __builtin_amdgcn_mfma_f32_16x16x32_f16(a, bfr[2][kt], acc2, 0,0,0);
    }
    {
      int col0 = (base+0)*16 + (lane&15);
      int col1 = (base+1)*16 + (lane&15);
      #pragma unroll
      for (int r=0;r<4;r++){ dls[drow+r][col0]=acc0[r]; dls[drow+r][col1]=acc1[r]; }
      if (cnt>2){
        int col2 = (base+2)*16 + (lane&15);
        #pragma unroll
        for (int r=0;r<4;r++) dls[drow+r][col2]=acc2[r];
      }
    }
    __syncthreads();
    // ---- cell phase ----
    #pragma unroll
    for (int k=0;k<3;k++){
      if (valid[k]){
        int b=bl[k], u=uu[k];
        float pi = dls[b][u]       + pf[k*4+0];
        float pfg= dls[b][u+150]   + pf[k*4+1];
        float pg = dls[b][u+300]   + pf[k*4+2];
        float po = dls[b][u+450]   + pf[k*4+3];
        float ig=hsig(pi), fg=hsig(pfg), og=hsig(po), gg=ftanh(pg);
        c[k] = fg*c[k] + ig*gg;
        float hv = og*ftanh(c[k]);
        m[k] = fmaxf(m[k], hv);
        hlast[k] = hv;
        hh[b][u] = (_Float16)hv;
      }
    }
    #pragma unroll
    for (int j=0;j<12;j++) pf[j]=pn[j];
    __syncthreads();
  }

  // ---- persist state ----
  #pragma unroll
  for (int k=0;k<3;k++){
    if (valid[k]){
      size_t gi = ((size_t)(dir*B_ + b0 + bl[k]))*HSTR + uu[k];
      cst[gi]=c[k]; mst[gi]=m[k]; hst[gi]=hlast[k];
      if (last) pooled[(size_t)(b0+bl[k])*300 + dir*HID + uu[k]] = m[k];
    }
  }
}

// ---------------- tail: AdaBN2 stats ----------------
__global__ void k_stats2(const float* __restrict__ pooled,
    const float* __restrict__ g2, const float* __restrict__ b2,
    float* __restrict__ a2, float* __restrict__ d2){
  int f = threadIdx.x;
  if (f >= 300) return;
  float s=0.f,q=0.f;
  for (int b=0;b<B_;b++){ float v = pooled[(size_t)b*300+f]; s+=v; q+=v*v; }
  float m = s*(1.f/B_), var = q*(1.f/B_) - m*m;
  float a = g2[f]*rsqrtf(var+EPS);
  a2[f]=a; d2[f]=b2[f]-m*a;
}

// ---------------- fc1 (+folded AdaBN2) + relu ----------------
__global__ void k_fc1(const float* __restrict__ pooled,
    const float* __restrict__ a2, const float* __restrict__ d2,
    const float* __restrict__ w1, const float* __restrict__ fb1,
    float* __restrict__ z1){
  int o = blockIdx.x*256 + threadIdx.x;
  if (o >= B_*50) return;
  int b = o/50, j = o%50;
  float acc = fb1[j];
  for (int f=0;f<300;f++)
    acc += (a2[f]*pooled[(size_t)b*300+f] + d2[f]) * w1[j*300+f];
  z1[o] = fmaxf(acc,0.f);
}

// ---------------- AdaBN3 stats ----------------
__global__ void k_stats3(const float* __restrict__ z1,
    const float* __restrict__ g3, const float* __restrict__ b3,
    float* __restrict__ a3, float* __restrict__ d3){
  int f = threadIdx.x;
  if (f >= 50) return;
  float s=0.f,q=0.f;
  for (int b=0;b<B_;b++){ float v = z1[(size_t)b*50+f]; s+=v; q+=v*v; }
  float m = s*(1.f/B_), var = q*(1.f/B_) - m*m;
  float a = g3[f]*rsqrtf(var+EPS);
  a3[f]=a; d3[f]=b3[f]-m*a;
}

// ---------------- fc2 (+folded AdaBN3) + softmax ----------------
__global__ void k_fc2(const float* __restrict__ z1,
    const float* __restrict__ a3, const float* __restrict__ d3,
    const float* __restrict__ w2, const float* __restrict__ fb2,
    float* __restrict__ out){
  int b = blockIdx.x;
  int t = threadIdx.x;
  __shared__ float zl[50];
  __shared__ float lg[10];
  if (t<50) zl[t] = a3[t]*z1[(size_t)b*50+t] + d3[t];
  __syncthreads();
  if (t<10){
    float acc = fb2[t];
    for (int j=0;j<50;j++) acc += zl[j]*w2[t*50+j];
    lg[t]=acc;
  }
  __syncthreads();
  if (t<10){
    float m = lg[0];
    #pragma unroll
    for (int i=1;i<10;i++) m = fmaxf(m,lg[i]);
    float s = 0.f;
    #pragma unroll
    for (int i=0;i<10;i++) s += expf(lg[i]-m);
    out[(size_t)b*10+t] = expf(lg[t]-m)/s;
  }
}

extern "C" void kernel_launch(void* const* d_in, const int* in_sizes, int n_in,
                              void* d_out, int out_size, void* d_ws, size_t ws_size,
                              hipStream_t stream) {
  const float* x    = (const float*)d_in[0];
  const float* cw   = (const float*)d_in[1];
  const float* cb   = (const float*)d_in[2];
  const float* g1   = (const float*)d_in[3];
  const float* b1v  = (const float*)d_in[4];
  const float* wihf = (const float*)d_in[5];
  const float* whhf = (const float*)d_in[6];
  const float* bihf = (const float*)d_in[7];
  const float* bhhf = (const float*)d_in[8];
  const float* wihb = (const float*)d_in[9];
  const float* whhb = (const float*)d_in[10];
  const float* bihb = (const float*)d_in[11];
  const float* bhhb = (const float*)d_in[12];
  const float* g2   = (const float*)d_in[13];
  const float* b2   = (const float*)d_in[14];
  const float* w1   = (const float*)d_in[15];
  const float* fb1  = (const float*)d_in[16];
  const float* g3   = (const float*)d_in[17];
  const float* b3   = (const float*)d_in[18];
  const float* w2   = (const float*)d_in[19];
  const float* fb2  = (const float*)d_in[20];
  float* out = (float*)d_out;

  uint8_t* base = (uint8_t*)d_ws;
  size_t off = 0;
  auto alloc = [&](size_t nfloats)->float*{
    float* p = (float*)(base + off);
    off = (off + nfloats*4 + 255) & ~(size_t)255;
    return p;
  };
  float* y      = alloc((size_t)B_*LOUT*NF);
  float* st     = alloc(256);
  float* wTf    = alloc((size_t)NF*NPAD);
  float* wTb    = alloc((size_t)NF*NPAD);
  float* bef    = alloc(NPAD);
  float* beb    = alloc(NPAD);
  float* wfrag  = alloc((size_t)2*NT_*KT_*64*8/2);   // halfs -> floats
  float* hst    = alloc((size_t)2*B_*HSTR);
  float* cst    = alloc((size_t)2*B_*HSTR);
  float* mst    = alloc((size_t)2*B_*HSTR);
  float* pooled = alloc((size_t)B_*300);
  float* a2     = alloc(320);
  float* d2     = alloc(320);
  float* z1     = alloc((size_t)B_*50);
  float* a3     = alloc(64);
  float* d3     = alloc(64);
  size_t fixedEnd = off;

  size_t per_t = (size_t)2*B_*NPAD*4;
  size_t avail = (ws_size > fixedEnd + 4096) ? (ws_size - fixedEnd - 4096) : 0;
  int tcmax = (int)(avail / per_t);
  if (tcmax < 1) tcmax = 1;
  if (tcmax > LOUT) tcmax = LOUT;
  int nch = (LOUT + tcmax - 1) / tcmax;
  int TC = (LOUT + nch - 1) / nch;
  float* pref = alloc((size_t)TC*B_*NPAD);
  float* preb = alloc((size_t)TC*B_*NPAD);

  hipMemsetAsync(st, 0, 256*4, stream);
  k_conv<<<dim3((LOUT+3)/4, B_), 512, 0, stream>>>(x, cw, cb, y);
  k_stats1<<<1024, 256, 0, stream>>>(y, st);
  k_prep<<<(2*NPAD+255)/256, 256, 0, stream>>>(st, g1, b1v, wihf, wihb,
                                               bihf, bhhf, bihb, bhhb,
                                               wTf, wTb, bef, beb);
  k_prep_whh<<<(2*NT_*KT_*64+255)/256, 256, 0, stream>>>(whhf, whhb, (_Float16*)wfrag);

  int t0 = 0; int first = 1;
  while (t0 < LOUT){
    int tc = (TC < LOUT - t0) ? TC : (LOUT - t0);
    int lastc = (t0 + tc >= LOUT) ? 1 : 0;
    k_proj<<<dim3(tc*4, 5, 2), 256, 0, stream>>>(y, wTf, wTb, bef, beb,
                                                 pref, preb, t0, tc);
    k_rec2<<<64, 1024, 0, stream>>>((const _Float16*)wfrag, pref, preb,
                                    hst, cst, mst, pooled, tc, first, lastc);
    t0 += tc; first = 0;
  }
  k_stats2<<<1, 320, 0, stream>>>(pooled, g2, b2, a2, d2);
  k_fc1<<<(B_*50+255)/256, 256, 0, stream>>>(pooled, a2, d2, w1, fb1, z1);
  k_stats3<<<1, 64, 0, stream>>>(z1, g3, b3, a3, d3);
  k_fc2<<<B_, 64, 0, stream>>>(z1, a3, d3, w2, fb2, out);
}

// Round 6
// 1356.479 us; speedup vs baseline: 5.6874x; 1.4136x over previous
//
#include <hip/hip_runtime.h>
#include <math.h>

#define B_   512
#define T_   800
#define FIN  3
#define NF   128
#define KW   15
#define HID  150
#define LOUT 393
#define G4   600
#define NPAD 640
#define EPS  1e-5f

#define NT_  38          // whh N tiles of 16 over 608
#define KT_  5           // whh K tiles of 32 over 160
#define HSTR 152
#define PNT  40          // wih N tiles of 16 over 640
#define PKT  4           // wih K tiles of 32 over 128

typedef _Float16 half8 __attribute__((ext_vector_type(8)));
typedef float f32x4 __attribute__((ext_vector_type(4)));

__device__ __forceinline__ float hsig(float x){ return fminf(fmaxf(0.2f*x+0.5f,0.f),1.f); }
__device__ __forceinline__ float ftanh(float x){ float e=__expf(2.f*x); return 1.f - 2.f/(e+1.f); }

// ------- conv + relu + maxpool2 + f16 store + AdaBN1 stats (fused) -------
__global__ __launch_bounds__(512) void k_conv2(const float* __restrict__ x,
        const float* __restrict__ cw, const float* __restrict__ cb,
        _Float16* __restrict__ y16, float* __restrict__ st){
  __shared__ float xs[FIN][800];
  __shared__ float wl[NF*FIN*KW];      // 5760
  __shared__ float rs[4][128], rq[4][128];
  int tid = threadIdx.x;
  int b = blockIdx.x;
  for (int i=tid;i<FIN*800;i+=512) (&xs[0][0])[i] = x[(size_t)b*(FIN*T_) + i];
  for (int i=tid;i<NF*FIN*KW;i+=512) wl[i]=cw[i];
  __syncthreads();
  int c = tid & 127, li = tid >> 7;
  float wr[FIN*KW];
  #pragma unroll
  for (int i=0;i<FIN*KW;i++) wr[i]=wl[c*FIN*KW+i];
  float cbv = cb[c];
  float s=0.f, q=0.f;
  for (int l=li; l<LOUT; l+=4){
    float a0=0.f, a1=0.f;
    #pragma unroll
    for (int f=0;f<FIN;f++){
      const float2* xp = (const float2*)&xs[f][0] + l;   // -> xs[f][2l]
      float xv[16];
      #pragma unroll
      for (int p=0;p<8;p++){ float2 v=xp[p]; xv[2*p]=v.x; xv[2*p+1]=v.y; }
      #pragma unroll
      for (int k=0;k<KW;k++){ float w=wr[f*KW+k]; a0 += w*xv[k]; a1 += w*xv[k+1]; }
    }
    float v = fmaxf(fmaxf(a0,a1)+cbv, 0.f);
    y16[((size_t)b*LOUT + l)*NF + c] = (_Float16)v;
    s += v; q += v*v;
  }
  rs[li][c]=s; rq[li][c]=q;
  __syncthreads();
  if (tid < 128){
    float ts = rs[0][c]+rs[1][c]+rs[2][c]+rs[3][c];
    float tq = rq[0][c]+rq[1][c]+rq[2][c]+rq[3][c];
    atomicAdd(&st[c], ts);
    atomicAdd(&st[128+c], tq);
  }
}

// -------- bias fold: be[g] = b_ih+b_hh + sum_f d[f]*w_ih[g][f] --------
__global__ void k_prep_bias(const float* __restrict__ st,
    const float* __restrict__ g1, const float* __restrict__ b1v,
    const float* __restrict__ wf, const float* __restrict__ wb,
    const float* __restrict__ bif, const float* __restrict__ bhf,
    const float* __restrict__ bib, const float* __restrict__ bhb,
    float* __restrict__ bef, float* __restrict__ beb){
  int id = blockIdx.x*256 + threadIdx.x;
  if (id >= 2*NPAD) return;
  int dir = id/NPAD, g = id%NPAD;
  float* be = dir? beb : bef;
  if (g >= G4){ be[g]=0.f; return; }
  const float* wih = dir? wb : wf;
  float bias = dir? (bib[g]+bhb[g]) : (bif[g]+bhf[g]);
  const float Ninv = 1.f/((float)B_*(float)LOUT);
  for (int f=0;f<NF;f++){
    float m = st[f]*Ninv;
    float var = st[NF+f]*Ninv - m*m;
    float a = g1[f]*rsqrtf(var+EPS);
    float d = b1v[f] - m*a;
    bias += d*wih[g*NF+f];
  }
  be[g] = bias;
}

// -------- pack AdaBN-folded w_ih into f16 MFMA B-fragments --------
// wT16[dir][nt][kt][lane][8]: n = nt*16+(l&15), k = kt*32+(l>>4)*8+j
__global__ void k_prep_wih(const float* __restrict__ st,
    const float* __restrict__ g1,
    const float* __restrict__ wf, const float* __restrict__ wb,
    _Float16* __restrict__ wT16){
  int id = blockIdx.x*256 + threadIdx.x;
  if (id >= 2*PNT*PKT*64) return;
  int lane = id & 63;
  int kt = (id>>6) & 3;
  int nt = (id>>8) % PNT;
  int dir = id / (PNT*PKT*64);
  const float* wih = dir? wb : wf;
  int n = nt*16 + (lane&15);
  int kb = kt*32 + (lane>>4)*8;
  const float Ninv = 1.f/((float)B_*(float)LOUT);
  half8 v;
  #pragma unroll
  for (int j=0;j<8;j++){
    int k = kb+j;
    float m = st[k]*Ninv;
    float var = st[NF+k]*Ninv - m*m;
    float a = g1[k]*rsqrtf(var+EPS);
    float f = (n < G4) ? wih[(size_t)n*NF + k]*a : 0.f;
    v[j] = (_Float16)f;
  }
  *(half8*)&wT16[(size_t)id*8] = v;
}

// -------- pack w_hh into f16 MFMA B-fragments (unchanged layout) --------
__global__ void k_prep_whh(const float* __restrict__ whf, const float* __restrict__ whb,
                           _Float16* __restrict__ wfrag){
  int id = blockIdx.x*256 + threadIdx.x;
  if (id >= 2*NT_*KT_*64) return;
  int lane = id & 63;
  int rest = id >> 6;
  int kt = rest % KT_;
  int nt = (rest/KT_) % NT_;
  int dir = rest / (KT_*NT_);
  const float* wh = dir? whb : whf;
  int n = nt*16 + (lane&15);
  int kb = kt*32 + (lane>>4)*8;
  half8 v;
  #pragma unroll
  for (int j=0;j<8;j++){
    int k = kb + j;
    float f = (n < G4 && k < HID) ? wh[(size_t)n*HID + k] : 0.f;
    v[j] = (_Float16)f;
  }
  *(half8*)&wfrag[(size_t)id*8] = v;
}

// ---------------- projection via f16 MFMA ----------------
// BM=128 (4 waves x 2 mtiles), BN=128 (8 ntiles), K=128 (4 ktiles).
// A-frags straight from L2 (one 64B line per row per kt). Out via LDS, f16.
__global__ __launch_bounds__(256) void k_proj2(const _Float16* __restrict__ y16,
    const _Float16* __restrict__ wT16,
    const float* __restrict__ bef, const float* __restrict__ beb,
    _Float16* __restrict__ pre16f, _Float16* __restrict__ pre16b,
    int t0f, int tc){
  __shared__ _Float16 Ds[128*136];
  __shared__ float bs[128];
  int dir = blockIdx.z;
  const _Float16* wfp = wT16 + (size_t)dir*PNT*PKT*64*8;
  const float* be = dir? beb : bef;
  _Float16* pre = dir? pre16b : pre16f;
  int tid = threadIdx.x, lane = tid&63, w = tid>>6;
  int trel = blockIdx.x>>2, bb = (blockIdx.x&3)*128;
  int t = dir ? (LOUT-1-t0f-trel) : (t0f+trel);
  int n0 = blockIdx.y*128;
  if (tid < 32) *(float4*)&bs[tid*4] = *(const float4*)&be[n0 + tid*4];

  f32x4 acc[2][8];
  #pragma unroll
  for (int i=0;i<2;i++)
    #pragma unroll
    for (int j=0;j<8;j++) acc[i][j] = (f32x4){0,0,0,0};

  int arow = lane&15, aq = (lane>>4)*8;
  const _Float16* a0p = y16 + ((size_t)(bb + (2*w)*16 + arow)*LOUT + t)*NF + aq;
  const _Float16* a1p = a0p + (size_t)16*LOUT*NF;
  int nb = n0 >> 4;
  #pragma unroll
  for (int kt=0; kt<PKT; kt++){
    half8 a0 = *(const half8*)(a0p + kt*32);
    half8 a1 = *(const half8*)(a1p + kt*32);
    #pragma unroll
    for (int nt=0; nt<8; nt++){
      half8 bf = *(const half8*)&wfp[(size_t)(((nb+nt)*PKT + kt)*64 + lane)*8];
      acc[0][nt] = __builtin_amdgcn_mfma_f32_16x16x32_f16(a0, bf, acc[0][nt], 0,0,0);
      acc[1][nt] = __builtin_amdgcn_mfma_f32_16x16x32_f16(a1, bf, acc[1][nt], 0,0,0);
    }
  }
  __syncthreads();   // bs ready; Ds free
  int dcol = lane&15, dq = (lane>>4)*4;
  #pragma unroll
  for (int mi=0; mi<2; mi++){
    int rowb = (2*w+mi)*16 + dq;
    #pragma unroll
    for (int nt=0; nt<8; nt++){
      int colL = nt*16 + dcol;
      float bv = bs[colL];
      #pragma unroll
      for (int r=0;r<4;r++)
        Ds[(rowb+r)*136 + colL] = (_Float16)(acc[mi][nt][r] + bv);
    }
  }
  __syncthreads();
  int row = tid>>1, h = tid&1;
  const _Float16* src = &Ds[row*136 + h*64];
  _Float16* dst = pre + ((size_t)(trel*B_ + bb + row))*NPAD + n0 + h*64;
  #pragma unroll
  for (int qq=0; qq<8; qq++)
    *(float4*)(dst + qq*8) = *(const float4*)(src + qq*8);
}

// ---------------- recurrence via f16 MFMA (f16 pre reads) ----------------
__global__ __launch_bounds__(1024)
__attribute__((amdgpu_waves_per_eu(4, 4)))
void k_rec2(const _Float16* __restrict__ wfrag,
            const _Float16* __restrict__ pref, const _Float16* __restrict__ preb,
            float* __restrict__ hst, float* __restrict__ cst, float* __restrict__ mst,
            float* __restrict__ pooled, int tc, int first, int last){
  int dir = blockIdx.x >> 5;
  int b0 = (blockIdx.x & 31) * 16;
  const _Float16* pre = dir? preb : pref;
  int tid = threadIdx.x;
  int lane = tid & 63, w = tid >> 6;

  __shared__ __align__(16) _Float16 hh[16][168];
  __shared__ float dls[16][612];

  int cnt  = (w<6) ? 3 : 2;
  int base = (w<6) ? 3*w : 18 + 2*(w-6);
  const _Float16* wf = wfrag + (size_t)dir*NT_*KT_*64*8;
  half8 bfr[3][5];
  #pragma unroll
  for (int i=0;i<3;i++){
    #pragma unroll
    for (int kt=0;kt<KT_;kt++){
      int ntc = (i<cnt)? (base+i) : base;
      bfr[i][kt] = *(const half8*)&wf[(size_t)((ntc*KT_+kt)*64 + lane)*8];
    }
  }

  int bl[3], uu[3], blc[3];
  bool valid[3];
  #pragma unroll
  for (int k=0;k<3;k++){
    int id = tid + k*1024;
    int b = id / HSTR, u = id - b*HSTR;
    bl[k]=b; uu[k]=u; blc[k]=b & 15;
    valid[k] = (id < 16*HSTR) && (u < HID);
  }

  for (int i=tid; i<16*168; i+=1024) (&hh[0][0])[i] = (_Float16)0.f;
  __syncthreads();
  float c[3], m[3], hlast[3];
  #pragma unroll
  for (int k=0;k<3;k++){ c[k]=0.f; m[k]=-1e30f; hlast[k]=0.f; }
  if (!first){
    #pragma unroll
    for (int k=0;k<3;k++){
      if (valid[k]){
        size_t gi = ((size_t)(dir*B_ + b0 + bl[k]))*HSTR + uu[k];
        c[k]=cst[gi]; m[k]=mst[gi];
        float hv = hst[gi]; hlast[k]=hv;
        hh[bl[k]][uu[k]] = (_Float16)hv;
      }
    }
  }
  float pf[12];
  #pragma unroll
  for (int k=0;k<3;k++){
    const _Float16* pr = pre + ((size_t)(b0 + blc[k]))*NPAD + uu[k];
    #pragma unroll
    for (int g=0;g<4;g++) pf[k*4+g] = (float)pr[g*HID];
  }
  __syncthreads();

  int arow = lane & 15;
  int koff = (lane>>4)*8;
  int drow = (lane>>4)*4;

  for (int t=0; t<tc; t++){
    float pn[12];
    #pragma unroll
    for (int j=0;j<12;j++) pn[j]=0.f;
    if (t+1 < tc){
      #pragma unroll
      for (int k=0;k<3;k++){
        const _Float16* pr = pre + ((size_t)(t+1)*B_ + b0 + blc[k])*NPAD + uu[k];
        #pragma unroll
        for (int g=0;g<4;g++) pn[k*4+g] = (float)pr[g*HID];
      }
    }
    f32x4 acc0={0,0,0,0}, acc1={0,0,0,0}, acc2={0,0,0,0};
    #pragma unroll
    for (int kt=0; kt<KT_; kt++){
      half8 a = *(const half8*)&hh[arow][kt*32 + koff];
      acc0 = __builtin_amdgcn_mfma_f32_16x16x32_f16(a, bfr[0][kt], acc0, 0,0,0);
      acc1 = __builtin_amdgcn_mfma_f32_16x16x32_f16(a, bfr[1][kt], acc1, 0,0,0);
      if (cnt>2) acc2 = __builtin_amdgcn_mfma_f32_16x16x32_f16(a, bfr[2][kt], acc2, 0,0,0);
    }
    {
      int col0 = (base+0)*16 + (lane&15);
      int col1 = (base+1)*16 + (lane&15);
      #pragma unroll
      for (int r=0;r<4;r++){ dls[drow+r][col0]=acc0[r]; dls[drow+r][col1]=acc1[r]; }
      if (cnt>2){
        int col2 = (base+2)*16 + (lane&15);
        #pragma unroll
        for (int r=0;r<4;r++) dls[drow+r][col2]=acc2[r];
      }
    }
    __syncthreads();
    #pragma unroll
    for (int k=0;k<3;k++){
      if (valid[k]){
        int b=bl[k], u=uu[k];
        float pi = dls[b][u]       + pf[k*4+0];
        float pfg= dls[b][u+150]   + pf[k*4+1];
        float pg = dls[b][u+300]   + pf[k*4+2];
        float po = dls[b][u+450]   + pf[k*4+3];
        float ig=hsig(pi), fg=hsig(pfg), og=hsig(po), gg=ftanh(pg);
        c[k] = fg*c[k] + ig*gg;
        float hv = og*ftanh(c[k]);
        m[k] = fmaxf(m[k], hv);
        hlast[k] = hv;
        hh[b][u] = (_Float16)hv;
      }
    }
    #pragma unroll
    for (int j=0;j<12;j++) pf[j]=pn[j];
    __syncthreads();
  }

  #pragma unroll
  for (int k=0;k<3;k++){
    if (valid[k]){
      size_t gi = ((size_t)(dir*B_ + b0 + bl[k]))*HSTR + uu[k];
      cst[gi]=c[k]; mst[gi]=m[k]; hst[gi]=hlast[k];
      if (last) pooled[(size_t)(b0+bl[k])*300 + dir*HID + uu[k]] = m[k];
    }
  }
}

// ---------------- tails ----------------
__global__ void k_stats2(const float* __restrict__ pooled,
    const float* __restrict__ g2, const float* __restrict__ b2,
    float* __restrict__ a2, float* __restrict__ d2){
  int f = threadIdx.x;
  if (f >= 300) return;
  float s=0.f,q=0.f;
  for (int b=0;b<B_;b++){ float v = pooled[(size_t)b*300+f]; s+=v; q+=v*v; }
  float m = s*(1.f/B_), var = q*(1.f/B_) - m*m;
  float a = g2[f]*rsqrtf(var+EPS);
  a2[f]=a; d2[f]=b2[f]-m*a;
}

__global__ void k_fc1(const float* __restrict__ pooled,
    const float* __restrict__ a2, const float* __restrict__ d2,
    const float* __restrict__ w1, const float* __restrict__ fb1,
    float* __restrict__ z1){
  int o = blockIdx.x*256 + threadIdx.x;
  if (o >= B_*50) return;
  int b = o/50, j = o%50;
  float acc = fb1[j];
  for (int f=0;f<300;f++)
    acc += (a2[f]*pooled[(size_t)b*300+f] + d2[f]) * w1[j*300+f];
  z1[o] = fmaxf(acc,0.f);
}

__global__ void k_stats3(const float* __restrict__ z1,
    const float* __restrict__ g3, const float* __restrict__ b3,
    float* __restrict__ a3, float* __restrict__ d3){
  int f = threadIdx.x;
  if (f >= 50) return;
  float s=0.f,q=0.f;
  for (int b=0;b<B_;b++){ float v = z1[(size_t)b*50+f]; s+=v; q+=v*v; }
  float m = s*(1.f/B_), var = q*(1.f/B_) - m*m;
  float a = g3[f]*rsqrtf(var+EPS);
  a3[f]=a; d3[f]=b3[f]-m*a;
}

__global__ void k_fc2(const float* __restrict__ z1,
    const float* __restrict__ a3, const float* __restrict__ d3,
    const float* __restrict__ w2, const float* __restrict__ fb2,
    float* __restrict__ out){
  int b = blockIdx.x;
  int t = threadIdx.x;
  __shared__ float zl[50];
  __shared__ float lg[10];
  if (t<50) zl[t] = a3[t]*z1[(size_t)b*50+t] + d3[t];
  __syncthreads();
  if (t<10){
    float acc = fb2[t];
    for (int j=0;j<50;j++) acc += zl[j]*w2[t*50+j];
    lg[t]=acc;
  }
  __syncthreads();
  if (t<10){
    float m = lg[0];
    #pragma unroll
    for (int i=1;i<10;i++) m = fmaxf(m,lg[i]);
    float s = 0.f;
    #pragma unroll
    for (int i=0;i<10;i++) s += expf(lg[i]-m);
    out[(size_t)b*10+t] = expf(lg[t]-m)/s;
  }
}

extern "C" void kernel_launch(void* const* d_in, const int* in_sizes, int n_in,
                              void* d_out, int out_size, void* d_ws, size_t ws_size,
                              hipStream_t stream) {
  const float* x    = (const float*)d_in[0];
  const float* cw   = (const float*)d_in[1];
  const float* cb   = (const float*)d_in[2];
  const float* g1   = (const float*)d_in[3];
  const float* b1v  = (const float*)d_in[4];
  const float* wihf = (const float*)d_in[5];
  const float* whhf = (const float*)d_in[6];
  const float* bihf = (const float*)d_in[7];
  const float* bhhf = (const float*)d_in[8];
  const float* wihb = (const float*)d_in[9];
  const float* whhb = (const float*)d_in[10];
  const float* bihb = (const float*)d_in[11];
  const float* bhhb = (const float*)d_in[12];
  const float* g2   = (const float*)d_in[13];
  const float* b2   = (const float*)d_in[14];
  const float* w1   = (const float*)d_in[15];
  const float* fb1  = (const float*)d_in[16];
  const float* g3   = (const float*)d_in[17];
  const float* b3   = (const float*)d_in[18];
  const float* w2   = (const float*)d_in[19];
  const float* fb2  = (const float*)d_in[20];
  float* out = (float*)d_out;

  uint8_t* base = (uint8_t*)d_ws;
  size_t off = 0;
  auto allocB = [&](size_t nbytes)->uint8_t*{
    uint8_t* p = base + off;
    off = (off + nbytes + 255) & ~(size_t)255;
    return p;
  };
  _Float16* y16   = (_Float16*)allocB((size_t)B_*LOUT*NF*2);
  float* st       = (float*)allocB(256*4);
  _Float16* wT16  = (_Float16*)allocB((size_t)2*PNT*PKT*64*8*2);
  float* bef      = (float*)allocB(NPAD*4);
  float* beb      = (float*)allocB(NPAD*4);
  _Float16* wfrag = (_Float16*)allocB((size_t)2*NT_*KT_*64*8*2);
  float* hst      = (float*)allocB((size_t)2*B_*HSTR*4);
  float* cst      = (float*)allocB((size_t)2*B_*HSTR*4);
  float* mst      = (float*)allocB((size_t)2*B_*HSTR*4);
  float* pooled   = (float*)allocB((size_t)B_*300*4);
  float* a2       = (float*)allocB(320*4);
  float* d2       = (float*)allocB(320*4);
  float* z1       = (float*)allocB((size_t)B_*50*4);
  float* a3       = (float*)allocB(64*4);
  float* d3       = (float*)allocB(64*4);
  size_t fixedEnd = off;

  size_t per_t = (size_t)2*B_*NPAD*2;   // both dirs, f16
  size_t avail = (ws_size > fixedEnd + 4096) ? (ws_size - fixedEnd - 4096) : 0;
  int tcmax = (int)(avail / per_t);
  if (tcmax < 1) tcmax = 1;
  if (tcmax > LOUT) tcmax = LOUT;
  int nch = (LOUT + tcmax - 1) / tcmax;
  int TC = (LOUT + nch - 1) / nch;
  _Float16* pre16f = (_Float16*)allocB((size_t)TC*B_*NPAD*2);
  _Float16* pre16b = (_Float16*)allocB((size_t)TC*B_*NPAD*2);

  hipMemsetAsync(st, 0, 256*4, stream);
  k_conv2<<<B_, 512, 0, stream>>>(x, cw, cb, y16, st);
  k_prep_bias<<<(2*NPAD+255)/256, 256, 0, stream>>>(st, g1, b1v, wihf, wihb,
                                                    bihf, bhhf, bihb, bhhb, bef, beb);
  k_prep_wih<<<(2*PNT*PKT*64+255)/256, 256, 0, stream>>>(st, g1, wihf, wihb, wT16);
  k_prep_whh<<<(2*NT_*KT_*64+255)/256, 256, 0, stream>>>(whhf, whhb, wfrag);

  int t0 = 0; int first = 1;
  while (t0 < LOUT){
    int tc = (TC < LOUT - t0) ? TC : (LOUT - t0);
    int lastc = (t0 + tc >= LOUT) ? 1 : 0;
    k_proj2<<<dim3(tc*4, 5, 2), 256, 0, stream>>>(y16, wT16, bef, beb,
                                                  pre16f, pre16b, t0, tc);
    k_rec2<<<64, 1024, 0, stream>>>(wfrag, pre16f, pre16b,
                                    hst, cst, mst, pooled, tc, first, lastc);
    t0 += tc; first = 0;
  }
  k_stats2<<<1, 320, 0, stream>>>(pooled, g2, b2, a2, d2);
  k_fc1<<<(B_*50+255)/256, 256, 0, stream>>>(pooled, a2, d2, w1, fb1, z1);
  k_stats3<<<1, 64, 0, stream>>>(z1, g3, b3, a3, d3);
  k_fc2<<<B_, 64, 0, stream>>>(z1, a3, d3, w2, fb2, out);
}